// Round 1
// baseline (1165.135 us; speedup 1.0000x reference)
//
#include <hip/hip_runtime.h>

// ---------------------------------------------------------------------------
// Problem constants (from reference)
// ---------------------------------------------------------------------------
constexpr int kB   = 8;
constexpr int kN   = 64;
constexpr int kE   = 192;
constexpr int kDin = 1024;
constexpr int kDp  = 256;
constexpr int kNN  = 4096;   // N*N
constexpr float kTauInv = 20.0f;   // 1/0.05

// ---------------------------------------------------------------------------
// Projection GEMM: h[4096 x 256] = [x1;x2;e1;e2] @ Wp + bp   (fp32 vector ALU)
// 64x64 tile, 256 threads, 4x4 micro-tile, K-chunks of 16 staged in LDS
// (k-major LDS layout so inner loop uses ds_read_b128).
// ---------------------------------------------------------------------------
__global__ __launch_bounds__(256) void gemm_proj(
    const float* __restrict__ x1, const float* __restrict__ x2,
    const float* __restrict__ e1, const float* __restrict__ e2,
    const float* __restrict__ Wp, const float* __restrict__ bp,
    float* __restrict__ hbuf)
{
    const int rt = blockIdx.y;      // 0..63 row tile
    const int ct = blockIdx.x;      // 0..3 col tile
    const int tid = threadIdx.x;
    const int tx = tid & 15, ty = tid >> 4;
    const int grow0 = rt * 64;
    const int col0  = ct * 64;

    const float* src; int lrow0;
    if (rt < 8)       { src = x1; lrow0 = grow0; }
    else if (rt < 16) { src = x2; lrow0 = grow0 - 512; }
    else if (rt < 40) { src = e1; lrow0 = grow0 - 1024; }
    else              { src = e2; lrow0 = grow0 - 2560; }

    __shared__ float As[16][68];   // [k][row]
    __shared__ float Ws[16][68];   // [k][col]

    const int arow = tid >> 2;          // 0..63
    const int acol = (tid & 3) * 4;     // 0,4,8,12 (k offset)
    const int wrow = tid >> 4;          // 0..15 (k)
    const int wcol = (tid & 15) * 4;    // 0..60

    float acc[4][4] = {};

    for (int k0 = 0; k0 < kDin; k0 += 16) {
        float4 a4 = *(const float4*)(src + (size_t)(lrow0 + arow) * kDin + k0 + acol);
        As[acol + 0][arow] = a4.x;
        As[acol + 1][arow] = a4.y;
        As[acol + 2][arow] = a4.z;
        As[acol + 3][arow] = a4.w;
        *(float4*)&Ws[wrow][wcol] =
            *(const float4*)(Wp + (size_t)(k0 + wrow) * kDp + col0 + wcol);
        __syncthreads();
#pragma unroll
        for (int kk = 0; kk < 16; ++kk) {
            float4 av = *(const float4*)&As[kk][ty * 4];
            float4 wv = *(const float4*)&Ws[kk][tx * 4];
            float a[4] = {av.x, av.y, av.z, av.w};
            float w[4] = {wv.x, wv.y, wv.z, wv.w};
#pragma unroll
            for (int i = 0; i < 4; ++i)
#pragma unroll
                for (int j = 0; j < 4; ++j)
                    acc[i][j] += a[i] * w[j];
        }
        __syncthreads();
    }
#pragma unroll
    for (int i = 0; i < 4; ++i)
#pragma unroll
        for (int j = 0; j < 4; ++j)
            hbuf[(size_t)(grow0 + ty * 4 + i) * kDp + col0 + tx * 4 + j] =
                acc[i][j] + bp[col0 + tx * 4 + j];
}

// ---------------------------------------------------------------------------
// BatchNorm statistics over rows, per segment (x1:512, x2:512, e1:1536, e2:1536)
// ---------------------------------------------------------------------------
__global__ __launch_bounds__(256) void bn_stats(const float* __restrict__ hbuf,
                                                float* __restrict__ stats)
{
    int seg = blockIdx.y, chunk = blockIdx.x, tid = threadIdx.x;
    int start = (seg == 0) ? 0 : (seg == 1 ? 512 : (seg == 2 ? 1024 : 2560));
    int len   = (seg < 2) ? 512 : 1536;
    int rows  = len >> 3;                 // 8 chunks
    int r0 = start + chunk * rows;
    float s = 0.f, s2 = 0.f;
    for (int r = 0; r < rows; ++r) {
        float v = hbuf[(size_t)(r0 + r) * kDp + tid];
        s += v; s2 += v * v;
    }
    atomicAdd(&stats[seg * 512 + tid], s);
    atomicAdd(&stats[seg * 512 + 256 + tid], s2);
}

__global__ void bn_fin(float* stats)
{
    int seg = blockIdx.x, tid = threadIdx.x;
    float n = (seg < 2) ? 512.f : 1536.f;
    float mu  = stats[seg * 512 + tid] / n;
    float var = stats[seg * 512 + 256 + tid] / n - mu * mu;
    stats[seg * 512 + tid] = mu;
    stats[seg * 512 + 256 + tid] = rsqrtf(var + 1e-5f);
}

// normalize + relu + row l2-normalize, in place (one block per row)
__global__ __launch_bounds__(256) void bn_norm_l2(float* hbuf,
                                                  const float* __restrict__ stats,
                                                  const float* __restrict__ gamma,
                                                  const float* __restrict__ beta)
{
    int r = blockIdx.x, tid = threadIdx.x;
    int seg = (r < 512) ? 0 : (r < 1024 ? 1 : (r < 2560 ? 2 : 3));
    float mu   = stats[seg * 512 + tid];
    float istd = stats[seg * 512 + 256 + tid];
    float v = hbuf[(size_t)r * kDp + tid];
    float p = fmaxf((v - mu) * istd * gamma[tid] + beta[tid], 0.f);
    float ss = p * p;
#pragma unroll
    for (int o = 32; o >= 1; o >>= 1) ss += __shfl_xor(ss, o);
    __shared__ float wsum[4];
    if ((tid & 63) == 0) wsum[tid >> 6] = ss;
    __syncthreads();
    float tot = wsum[0] + wsum[1] + wsum[2] + wsum[3];
    float scale = 1.f / fmaxf(sqrtf(tot), 1e-12f);
    hbuf[(size_t)r * kDp + tid] = p * scale;
}

// ---------------------------------------------------------------------------
// Batched NT GEMM: out[b] = scale * X[b] (M x 256) @ Y[b]^T (Nc x 256)
// used for Kp (M=Nc=64, scale=1) and Ke (M=Nc=192, scale=0.5)
// ---------------------------------------------------------------------------
__global__ __launch_bounds__(256) void gemm_nt(
    const float* __restrict__ X0, const float* __restrict__ Y0,
    float* __restrict__ outp, int M, int Nc, float scale)
{
    const int b = blockIdx.z;
    const int m0 = blockIdx.y * 64, n0 = blockIdx.x * 64;
    const int tid = threadIdx.x;
    const int tx = tid & 15, ty = tid >> 4;
    const float* X = X0 + (size_t)b * M * kDp;
    const float* Y = Y0 + (size_t)b * Nc * kDp;

    __shared__ float Xs[16][68];
    __shared__ float Ys[16][68];
    const int arow = tid >> 2, acol = (tid & 3) * 4;

    float acc[4][4] = {};
    for (int k0 = 0; k0 < kDp; k0 += 16) {
        float4 xa = *(const float4*)(X + (size_t)(m0 + arow) * kDp + k0 + acol);
        Xs[acol + 0][arow] = xa.x; Xs[acol + 1][arow] = xa.y;
        Xs[acol + 2][arow] = xa.z; Xs[acol + 3][arow] = xa.w;
        float4 ya = *(const float4*)(Y + (size_t)(n0 + arow) * kDp + k0 + acol);
        Ys[acol + 0][arow] = ya.x; Ys[acol + 1][arow] = ya.y;
        Ys[acol + 2][arow] = ya.z; Ys[acol + 3][arow] = ya.w;
        __syncthreads();
#pragma unroll
        for (int kk = 0; kk < 16; ++kk) {
            float4 xv = *(const float4*)&Xs[kk][ty * 4];
            float4 yv = *(const float4*)&Ys[kk][tx * 4];
            float a[4] = {xv.x, xv.y, xv.z, xv.w};
            float c[4] = {yv.x, yv.y, yv.z, yv.w};
#pragma unroll
            for (int i = 0; i < 4; ++i)
#pragma unroll
                for (int j = 0; j < 4; ++j)
                    acc[i][j] += a[i] * c[j];
        }
        __syncthreads();
    }
#pragma unroll
    for (int i = 0; i < 4; ++i)
#pragma unroll
        for (int j = 0; j < 4; ++j)
            outp[(size_t)b * M * Nc + (size_t)(m0 + ty * 4 + i) * Nc + n0 + tx * 4 + j] =
                scale * acc[i][j];
}

// ---------------------------------------------------------------------------
// Edge class dedup (representative = min edge index sharing (s,d) key)
// ---------------------------------------------------------------------------
__global__ void edge_prep(const int* __restrict__ s1, const int* __restrict__ d1,
                          const int* __restrict__ s2, const int* __restrict__ d2,
                          int* __restrict__ map1, int* __restrict__ map2)
{
    int b = blockIdx.x, i = threadIdx.x;
    if (i < kE) {
        atomicMin(&map1[b * kNN + s1[b * kE + i] * kN + d1[b * kE + i]], i);
        atomicMin(&map2[b * kNN + s2[b * kE + i] * kN + d2[b * kE + i]], i);
    }
}

// Accumulate class-pair sums Sagg[b][rep1][rep2] += Ke[b][i][j]
__global__ __launch_bounds__(256) void sagg_k(
    const int* __restrict__ s1, const int* __restrict__ d1,
    const int* __restrict__ s2, const int* __restrict__ d2,
    const float* __restrict__ Ke, const int* __restrict__ map1,
    const int* __restrict__ map2, float* __restrict__ Sagg)
{
    int idx = blockIdx.x * 256 + threadIdx.x;      // 0 .. 8*192*192-1
    int b = idx / (kE * kE);
    int rem = idx - b * kE * kE;
    int i = rem / kE, j = rem - i * kE;
    int key1 = s1[b * kE + i] * kN + d1[b * kE + i];
    int key2 = s2[b * kE + j] * kN + d2[b * kE + j];
    int r1 = map1[b * kNN + key1];
    int r2 = map2[b * kNN + key2];
    atomicAdd(&Sagg[(size_t)b * kE * kE + r1 * kE + r2], Ke[idx]);
}

// Count positive off-diagonal accumulated entries per row (canonical pairs only)
__global__ __launch_bounds__(256) void deg_count(
    const int* __restrict__ s1, const int* __restrict__ d1,
    const int* __restrict__ s2, const int* __restrict__ d2,
    const float* __restrict__ Sagg, const int* __restrict__ map1,
    const int* __restrict__ map2, int* __restrict__ degcnt)
{
    int idx = blockIdx.x * 256 + threadIdx.x;
    int b = idx / (kE * kE);
    int rem = idx - b * kE * kE;
    int i = rem / kE, j = rem - i * kE;
    int a1 = s1[b * kE + i], c1 = d1[b * kE + i];
    int a2 = s2[b * kE + j], c2 = d2[b * kE + j];
    if (map1[b * kNN + a1 * kN + c1] != i) return;
    if (map2[b * kNN + a2 * kN + c2] != j) return;
    float val = Sagg[(size_t)b * kE * kE + i * kE + j];
    int r = a2 * kN + a1, c = c2 * kN + c1;
    if (r != c && val > 0.0f) atomicAdd(&degcnt[b * kNN + r], 1);
}

// deg = max(count + (Kdiag>0), 1);  kdiag[b][r] = Kp[b][r&63][r>>6] (== x0)
__global__ __launch_bounds__(256) void deg_fin(const int* __restrict__ degcnt,
                                               const float* __restrict__ Kp,
                                               float* __restrict__ deg,
                                               float* __restrict__ kdiag)
{
    int idx = blockIdx.x * 256 + threadIdx.x;      // 0..32767
    int b = idx >> 12, r = idx & 4095;
    float kd = Kp[b * kNN + (r & 63) * kN + (r >> 6)];
    int d = degcnt[idx] + (kd > 0.0f ? 1 : 0);
    deg[idx] = fmaxf((float)d, 1.0f);
    kdiag[idx] = kd;
}

// ---------------------------------------------------------------------------
// Off-diagonal sparse message scatter: msg[b][r][:] += Ke[b][i][j] * x[b][c][:]
// ---------------------------------------------------------------------------
template <int C>
__global__ __launch_bounds__(256) void msg_scatter(
    const int* __restrict__ s1, const int* __restrict__ d1,
    const int* __restrict__ s2, const int* __restrict__ d2,
    const float* __restrict__ Ke, const float* __restrict__ x,
    float* __restrict__ msg)
{
    int idx = blockIdx.x * 256 + threadIdx.x;
    int b = idx / (kE * kE);
    int rem = idx - b * kE * kE;
    int i = rem / kE, j = rem - i * kE;
    int a1 = s1[b * kE + i], c1 = d1[b * kE + i];
    int a2 = s2[b * kE + j], c2 = d2[b * kE + j];
    int r = a2 * kN + a1, c = c2 * kN + c1;
    if (r == c) return;                      // diagonal is overwritten by set()
    float val = Ke[idx];
    const float* xc = x + (size_t)(b * kNN + c) * C;
    float* mr = msg + (size_t)(b * kNN + r) * C;
#pragma unroll
    for (int ch = 0; ch < C; ++ch) atomicAdd(&mr[ch], val * xc[ch]);
}

// ---------------------------------------------------------------------------
// Per-row: add diagonal term, divide by deg, h = relu(m@W+b), v = h@S+c
// writes h into xn[...,0:16] and v into vbuf
// ---------------------------------------------------------------------------
template <int C>
__global__ __launch_bounds__(256) void layer_fuse(
    const float* __restrict__ msg, const float* __restrict__ x,
    const float* __restrict__ kdiag, const float* __restrict__ deg,
    const float* __restrict__ W, const float* __restrict__ bb,
    const float* __restrict__ S, const float* __restrict__ c0,
    float* __restrict__ xn, float* __restrict__ vbuf)
{
    int idx = blockIdx.x * 256 + threadIdx.x;      // b*4096 + r
    float kd = kdiag[idx];
    float dg = deg[idx];
    float m[C];
#pragma unroll
    for (int c = 0; c < C; ++c)
        m[c] = (msg[(size_t)idx * C + c] + kd * x[(size_t)idx * C + c]) / dg;
    float h[16];
#pragma unroll
    for (int f = 0; f < 16; ++f) {
        float a = bb[f];
#pragma unroll
        for (int c = 0; c < C; ++c) a += m[c] * W[c * 16 + f];
        h[f] = fmaxf(a, 0.f);
    }
    float v = c0[0];
#pragma unroll
    for (int f = 0; f < 16; ++f) {
        v += h[f] * S[f];
        xn[(size_t)idx * 17 + f] = h[f];
    }
    vbuf[idx] = v;
}

// ---------------------------------------------------------------------------
// Sinkhorn in LDS. Layers: NR=64, input vbuf (transposed, *1/tau),
// output exp -> xn channel 16.  Final: NR=65, binv border, output -> d_out.
// 4 threads per row, quad shuffle reductions. 10 iterations.
// ---------------------------------------------------------------------------
template <int NR, bool FINAL>
__global__ __launch_bounds__(320) void sinkhorn_k(const float* __restrict__ vin,
                                                  float* __restrict__ outp,
                                                  const float* __restrict__ binvp)
{
    constexpr int STRIDE = (NR % 2 == 0) ? NR + 1 : NR;
    __shared__ float mat[NR][STRIDE];
    const int b = blockIdx.x;
    const int tid = threadIdx.x;

    float binv = 0.f;
    if (FINAL) binv = binvp[0];

    for (int idx = tid; idx < NR * NR; idx += blockDim.x) {
        int p = idx / NR, q = idx - p * NR;
        float val;
        if (FINAL) {
            val = (p < kN && q < kN) ? vin[b * kNN + q * kN + p] : binv;
        } else {
            val = vin[b * kNN + q * kN + p] * kTauInv;
        }
        mat[p][q] = val;
    }
    __syncthreads();

    const int r = tid >> 2, s = tid & 3;
    const bool act = r < NR;

    for (int it = 0; it < 10; ++it) {
        // axis 2 (rows): normalize over q for each p=r
        float m = -1e30f;
        if (act) for (int q = s; q < NR; q += 4) m = fmaxf(m, mat[r][q]);
        m = fmaxf(m, __shfl_xor(m, 1));
        m = fmaxf(m, __shfl_xor(m, 2));
        float sum = 0.f;
        if (act) for (int q = s; q < NR; q += 4) sum += __expf(mat[r][q] - m);
        sum += __shfl_xor(sum, 1);
        sum += __shfl_xor(sum, 2);
        float lse = m + __logf(sum);
        if (act) for (int q = s; q < NR; q += 4) mat[r][q] -= lse;
        __syncthreads();
        // axis 1 (cols): normalize over p for each q=r
        m = -1e30f;
        if (act) for (int p = s; p < NR; p += 4) m = fmaxf(m, mat[p][r]);
        m = fmaxf(m, __shfl_xor(m, 1));
        m = fmaxf(m, __shfl_xor(m, 2));
        sum = 0.f;
        if (act) for (int p = s; p < NR; p += 4) sum += __expf(mat[p][r] - m);
        sum += __shfl_xor(sum, 1);
        sum += __shfl_xor(sum, 2);
        lse = m + __logf(sum);
        if (act) for (int p = s; p < NR; p += 4) mat[p][r] -= lse;
        __syncthreads();
    }

    for (int idx = tid; idx < NR * NR; idx += blockDim.x) {
        int p = idx / NR, q = idx - p * NR;
        float e = __expf(mat[p][q]);
        if (FINAL) {
            if (p < kN && q < kN) outp[((size_t)b * kN + p) * kN + q] = e;
        } else {
            outp[(size_t)(b * kNN + q * kN + p) * 17 + 16] = e;
        }
    }
}

// ---------------------------------------------------------------------------
// Final projection over concat features: vfin = x @ Wc + bc
// ---------------------------------------------------------------------------
__global__ __launch_bounds__(256) void final_proj(const float* __restrict__ x,
                                                  const float* __restrict__ Wc,
                                                  const float* __restrict__ bc,
                                                  float* __restrict__ vfin)
{
    int idx = blockIdx.x * 256 + threadIdx.x;
    float v = bc[0];
#pragma unroll
    for (int c = 0; c < 17; ++c) v += x[(size_t)idx * 17 + c] * Wc[c];
    vfin[idx] = v;
}

// global max (values are positive exp() outputs -> uint compare is valid)
__global__ __launch_bounds__(256) void max_reduce(const float* __restrict__ outp,
                                                  unsigned* __restrict__ maxbuf)
{
    int idx = blockIdx.x * 256 + threadIdx.x;
    float v = outp[idx];
#pragma unroll
    for (int o = 32; o >= 1; o >>= 1) v = fmaxf(v, __shfl_xor(v, o));
    __shared__ float w[4];
    if ((threadIdx.x & 63) == 0) w[threadIdx.x >> 6] = v;
    __syncthreads();
    if (threadIdx.x == 0) {
        v = fmaxf(fmaxf(w[0], w[1]), fmaxf(w[2], w[3]));
        atomicMax(maxbuf, __float_as_uint(v));
    }
}

__global__ __launch_bounds__(256) void scale_out(float* __restrict__ outp,
                                                 const unsigned* __restrict__ maxbuf)
{
    int idx = blockIdx.x * 256 + threadIdx.x;
    outp[idx] = outp[idx] / __uint_as_float(maxbuf[0]);
}

// ---------------------------------------------------------------------------
extern "C" void kernel_launch(void* const* d_in, const int* in_sizes, int n_in,
                              void* d_out, int out_size, void* d_ws, size_t ws_size,
                              hipStream_t stream)
{
    (void)in_sizes; (void)n_in; (void)out_size; (void)ws_size;

    const float* x1    = (const float*)d_in[0];
    const float* x2    = (const float*)d_in[1];
    const float* e1    = (const float*)d_in[2];
    const float* e2    = (const float*)d_in[3];
    const float* Wp    = (const float*)d_in[4];
    const float* bp    = (const float*)d_in[5];
    const float* gamma = (const float*)d_in[6];
    const float* beta  = (const float*)d_in[7];
    const float* W0 = (const float*)d_in[8];
    const float* b0 = (const float*)d_in[9];
    const float* S0 = (const float*)d_in[10];
    const float* c0 = (const float*)d_in[11];
    const float* W1 = (const float*)d_in[12];
    const float* b1 = (const float*)d_in[13];
    const float* S1 = (const float*)d_in[14];
    const float* c1 = (const float*)d_in[15];
    const float* W2 = (const float*)d_in[16];
    const float* b2 = (const float*)d_in[17];
    const float* S2 = (const float*)d_in[18];
    const float* c2 = (const float*)d_in[19];
    const float* Wc = (const float*)d_in[20];
    const float* bc = (const float*)d_in[21];
    const float* binv = (const float*)d_in[22];
    const int* src1 = (const int*)d_in[23];
    const int* dst1 = (const int*)d_in[24];
    const int* src2 = (const int*)d_in[25];
    const int* dst2 = (const int*)d_in[26];

    float* out = (float*)d_out;
    float* wsf = (float*)d_ws;

    // workspace carve (floats)
    float* hbuf  = wsf;                    // 4096*256      = 1,048,576
    float* stats = hbuf + 1048576;         // 2048
    float* Kp    = stats + 2048;           // 8*64*64       = 32768
    float* Ke    = Kp + 32768;             // 8*192*192     = 294912
    float* Sagg  = Ke + 294912;            // 294912
    float* kdiag = Sagg + 294912;          // 32768  (also x0 / Kdiag)
    float* deg   = kdiag + 32768;          // 32768
    float* vbuf  = deg + 32768;            // 32768
    float* msg   = vbuf + 32768;           // 8*4096*17     = 557056
    float* xA    = msg + 557056;           // 557056
    float* xB    = xA + 557056;            // 557056
    int*   map1  = (int*)(xB + 557056);    // 32768
    int*   map2  = map1 + 32768;           // 32768
    int*   degcnt = map2 + 32768;          // 32768
    unsigned* maxbuf = (unsigned*)(degcnt + 32768);

    // zero/init the accumulation buffers
    hipMemsetAsync(stats, 0, 2048 * sizeof(float), stream);
    hipMemsetAsync(Sagg, 0, 294912 * sizeof(float), stream);
    hipMemsetAsync(map1, 0x7f, 2 * 32768 * sizeof(int), stream);  // map1+map2
    hipMemsetAsync(degcnt, 0, 32768 * sizeof(int), stream);
    hipMemsetAsync(maxbuf, 0, sizeof(unsigned), stream);

    // ---- projection + batchnorm + relu + l2norm ----
    gemm_proj<<<dim3(4, 64), 256, 0, stream>>>(x1, x2, e1, e2, Wp, bp, hbuf);
    bn_stats<<<dim3(8, 4), 256, 0, stream>>>(hbuf, stats);
    bn_fin<<<4, 256, 0, stream>>>(stats);
    bn_norm_l2<<<4096, 256, 0, stream>>>(hbuf, stats, gamma, beta);

    // ---- cosine similarity matrices ----
    gemm_nt<<<dim3(1, 1, 8), 256, 0, stream>>>(hbuf, hbuf + 512 * 256, Kp, 64, 64, 1.0f);
    gemm_nt<<<dim3(3, 3, 8), 256, 0, stream>>>(hbuf + 1024 * 256, hbuf + 2560 * 256, Ke, 192, 192, 0.5f);

    // ---- sparse K structure: class dedup, accumulated sums, degrees ----
    edge_prep<<<8, 192, 0, stream>>>(src1, dst1, src2, dst2, map1, map2);
    sagg_k<<<1152, 256, 0, stream>>>(src1, dst1, src2, dst2, Ke, map1, map2, Sagg);
    deg_count<<<1152, 256, 0, stream>>>(src1, dst1, src2, dst2, Sagg, map1, map2, degcnt);
    deg_fin<<<128, 256, 0, stream>>>(degcnt, Kp, deg, kdiag);

    // ---- layer 0 (C=1, x = kdiag = Kp^T flattened) ----
    hipMemsetAsync(msg, 0, 32768 * sizeof(float), stream);
    msg_scatter<1><<<1152, 256, 0, stream>>>(src1, dst1, src2, dst2, Ke, kdiag, msg);
    layer_fuse<1><<<128, 256, 0, stream>>>(msg, kdiag, kdiag, deg, W0, b0, S0, c0, xA, vbuf);
    sinkhorn_k<64, false><<<8, 256, 0, stream>>>(vbuf, xA, nullptr);

    // ---- layer 1 (C=17) ----
    hipMemsetAsync(msg, 0, 557056 * sizeof(float), stream);
    msg_scatter<17><<<1152, 256, 0, stream>>>(src1, dst1, src2, dst2, Ke, xA, msg);
    layer_fuse<17><<<128, 256, 0, stream>>>(msg, xA, kdiag, deg, W1, b1, S1, c1, xB, vbuf);
    sinkhorn_k<64, false><<<8, 256, 0, stream>>>(vbuf, xB, nullptr);

    // ---- layer 2 (C=17) ----
    hipMemsetAsync(msg, 0, 557056 * sizeof(float), stream);
    msg_scatter<17><<<1152, 256, 0, stream>>>(src1, dst1, src2, dst2, Ke, xB, msg);
    layer_fuse<17><<<128, 256, 0, stream>>>(msg, xB, kdiag, deg, W2, b2, S2, c2, xA, vbuf);
    sinkhorn_k<64, false><<<8, 256, 0, stream>>>(vbuf, xA, nullptr);

    // ---- final projection + bin-augmented sinkhorn + global max normalize ----
    final_proj<<<128, 256, 0, stream>>>(xA, Wc, bc, vbuf);
    sinkhorn_k<65, true><<<8, 320, 0, stream>>>(vbuf, out, binv);
    max_reduce<<<128, 256, 0, stream>>>(out, maxbuf);
    scale_out<<<128, 256, 0, stream>>>(out, maxbuf);
}

// Round 2
// 600.163 us; speedup vs baseline: 1.9414x; 1.9414x over previous
//
#include <hip/hip_runtime.h>

// ---------------------------------------------------------------------------
// Problem constants (from reference)
// ---------------------------------------------------------------------------
constexpr int kB   = 8;
constexpr int kN   = 64;
constexpr int kE   = 192;
constexpr int kDin = 1024;
constexpr int kDp  = 256;
constexpr int kNN  = 4096;   // N*N
constexpr float kTauInv = 20.0f;   // 1/0.05

// ---------------------------------------------------------------------------
// Projection GEMM: h[4096 x 256] = [x1;x2;e1;e2] @ Wp + bp   (fp32 vector ALU)
// ---------------------------------------------------------------------------
__global__ __launch_bounds__(256) void gemm_proj(
    const float* __restrict__ x1, const float* __restrict__ x2,
    const float* __restrict__ e1, const float* __restrict__ e2,
    const float* __restrict__ Wp, const float* __restrict__ bp,
    float* __restrict__ hbuf)
{
    const int rt = blockIdx.y;      // 0..63 row tile
    const int ct = blockIdx.x;      // 0..3 col tile
    const int tid = threadIdx.x;
    const int tx = tid & 15, ty = tid >> 4;
    const int grow0 = rt * 64;
    const int col0  = ct * 64;

    const float* src; int lrow0;
    if (rt < 8)       { src = x1; lrow0 = grow0; }
    else if (rt < 16) { src = x2; lrow0 = grow0 - 512; }
    else if (rt < 40) { src = e1; lrow0 = grow0 - 1024; }
    else              { src = e2; lrow0 = grow0 - 2560; }

    __shared__ float As[16][68];   // [k][row]
    __shared__ float Ws[16][68];   // [k][col]

    const int arow = tid >> 2;          // 0..63
    const int acol = (tid & 3) * 4;     // 0,4,8,12 (k offset)
    const int wrow = tid >> 4;          // 0..15 (k)
    const int wcol = (tid & 15) * 4;    // 0..60

    float acc[4][4] = {};

    for (int k0 = 0; k0 < kDin; k0 += 16) {
        float4 a4 = *(const float4*)(src + (size_t)(lrow0 + arow) * kDin + k0 + acol);
        As[acol + 0][arow] = a4.x;
        As[acol + 1][arow] = a4.y;
        As[acol + 2][arow] = a4.z;
        As[acol + 3][arow] = a4.w;
        *(float4*)&Ws[wrow][wcol] =
            *(const float4*)(Wp + (size_t)(k0 + wrow) * kDp + col0 + wcol);
        __syncthreads();
#pragma unroll
        for (int kk = 0; kk < 16; ++kk) {
            float4 av = *(const float4*)&As[kk][ty * 4];
            float4 wv = *(const float4*)&Ws[kk][tx * 4];
            float a[4] = {av.x, av.y, av.z, av.w};
            float w[4] = {wv.x, wv.y, wv.z, wv.w};
#pragma unroll
            for (int i = 0; i < 4; ++i)
#pragma unroll
                for (int j = 0; j < 4; ++j)
                    acc[i][j] += a[i] * w[j];
        }
        __syncthreads();
    }
#pragma unroll
    for (int i = 0; i < 4; ++i)
#pragma unroll
        for (int j = 0; j < 4; ++j)
            hbuf[(size_t)(grow0 + ty * 4 + i) * kDp + col0 + tx * 4 + j] =
                acc[i][j] + bp[col0 + tx * 4 + j];
}

// ---------------------------------------------------------------------------
// BatchNorm statistics over rows, per segment (x1:512, x2:512, e1:1536, e2:1536)
// ---------------------------------------------------------------------------
__global__ __launch_bounds__(256) void bn_stats(const float* __restrict__ hbuf,
                                                float* __restrict__ stats)
{
    int seg = blockIdx.y, chunk = blockIdx.x, tid = threadIdx.x;
    int start = (seg == 0) ? 0 : (seg == 1 ? 512 : (seg == 2 ? 1024 : 2560));
    int len   = (seg < 2) ? 512 : 1536;
    int rows  = len >> 3;                 // 8 chunks
    int r0 = start + chunk * rows;
    float s = 0.f, s2 = 0.f;
    for (int r = 0; r < rows; ++r) {
        float v = hbuf[(size_t)(r0 + r) * kDp + tid];
        s += v; s2 += v * v;
    }
    atomicAdd(&stats[seg * 512 + tid], s);
    atomicAdd(&stats[seg * 512 + 256 + tid], s2);
}

__global__ void bn_fin(float* stats)
{
    int seg = blockIdx.x, tid = threadIdx.x;
    float n = (seg < 2) ? 512.f : 1536.f;
    float mu  = stats[seg * 512 + tid] / n;
    float var = stats[seg * 512 + 256 + tid] / n - mu * mu;
    stats[seg * 512 + tid] = mu;
    stats[seg * 512 + 256 + tid] = rsqrtf(var + 1e-5f);
}

// normalize + relu + row l2-normalize, in place (one block per row)
__global__ __launch_bounds__(256) void bn_norm_l2(float* hbuf,
                                                  const float* __restrict__ stats,
                                                  const float* __restrict__ gamma,
                                                  const float* __restrict__ beta)
{
    int r = blockIdx.x, tid = threadIdx.x;
    int seg = (r < 512) ? 0 : (r < 1024 ? 1 : (r < 2560 ? 2 : 3));
    float mu   = stats[seg * 512 + tid];
    float istd = stats[seg * 512 + 256 + tid];
    float v = hbuf[(size_t)r * kDp + tid];
    float p = fmaxf((v - mu) * istd * gamma[tid] + beta[tid], 0.f);
    float ss = p * p;
#pragma unroll
    for (int o = 32; o >= 1; o >>= 1) ss += __shfl_xor(ss, o);
    __shared__ float wsum[4];
    if ((tid & 63) == 0) wsum[tid >> 6] = ss;
    __syncthreads();
    float tot = wsum[0] + wsum[1] + wsum[2] + wsum[3];
    float scale = 1.f / fmaxf(sqrtf(tot), 1e-12f);
    hbuf[(size_t)r * kDp + tid] = p * scale;
}

// ---------------------------------------------------------------------------
// Batched NT GEMM: out[b] = scale * X[b] (M x 256) @ Y[b]^T (Nc x 256)
// ---------------------------------------------------------------------------
__global__ __launch_bounds__(256) void gemm_nt(
    const float* __restrict__ X0, const float* __restrict__ Y0,
    float* __restrict__ outp, int M, int Nc, float scale)
{
    const int b = blockIdx.z;
    const int m0 = blockIdx.y * 64, n0 = blockIdx.x * 64;
    const int tid = threadIdx.x;
    const int tx = tid & 15, ty = tid >> 4;
    const float* X = X0 + (size_t)b * M * kDp;
    const float* Y = Y0 + (size_t)b * Nc * kDp;

    __shared__ float Xs[16][68];
    __shared__ float Ys[16][68];
    const int arow = tid >> 2, acol = (tid & 3) * 4;

    float acc[4][4] = {};
    for (int k0 = 0; k0 < kDp; k0 += 16) {
        float4 xa = *(const float4*)(X + (size_t)(m0 + arow) * kDp + k0 + acol);
        Xs[acol + 0][arow] = xa.x; Xs[acol + 1][arow] = xa.y;
        Xs[acol + 2][arow] = xa.z; Xs[acol + 3][arow] = xa.w;
        float4 ya = *(const float4*)(Y + (size_t)(n0 + arow) * kDp + k0 + acol);
        Ys[acol + 0][arow] = ya.x; Ys[acol + 1][arow] = ya.y;
        Ys[acol + 2][arow] = ya.z; Ys[acol + 3][arow] = ya.w;
        __syncthreads();
#pragma unroll
        for (int kk = 0; kk < 16; ++kk) {
            float4 xv = *(const float4*)&Xs[kk][ty * 4];
            float4 yv = *(const float4*)&Ys[kk][tx * 4];
            float a[4] = {xv.x, xv.y, xv.z, xv.w};
            float c[4] = {yv.x, yv.y, yv.z, yv.w};
#pragma unroll
            for (int i = 0; i < 4; ++i)
#pragma unroll
                for (int j = 0; j < 4; ++j)
                    acc[i][j] += a[i] * c[j];
        }
        __syncthreads();
    }
#pragma unroll
    for (int i = 0; i < 4; ++i)
#pragma unroll
        for (int j = 0; j < 4; ++j)
            outp[(size_t)b * M * Nc + (size_t)(m0 + ty * 4 + i) * Nc + n0 + tx * 4 + j] =
                scale * acc[i][j];
}

// ---------------------------------------------------------------------------
// Per-batch CSR: bucket edges of graph1 by s1, graph2 by s2.
// off*[b][65], lst*[b][192]
// ---------------------------------------------------------------------------
__global__ __launch_bounds__(256) void build_csr(
    const int* __restrict__ s1, const int* __restrict__ s2,
    int* __restrict__ off1, int* __restrict__ lst1,
    int* __restrict__ off2, int* __restrict__ lst2)
{
    int b = blockIdx.x, t = threadIdx.x;
    __shared__ int cnt1[64], cnt2[64], pos1[64], pos2[64];
    if (t < 64) { cnt1[t] = 0; cnt2[t] = 0; }
    __syncthreads();
    if (t < kE) {
        atomicAdd(&cnt1[s1[b * kE + t]], 1);
        atomicAdd(&cnt2[s2[b * kE + t]], 1);
    }
    __syncthreads();
    if (t == 0) {
        int a = 0, c = 0;
        for (int v = 0; v < 64; ++v) {
            pos1[v] = a; a += cnt1[v];
            pos2[v] = c; c += cnt2[v];
        }
    }
    __syncthreads();
    if (t < 64) { off1[b * 65 + t] = pos1[t]; off2[b * 65 + t] = pos2[t]; }
    if (t == 0) { off1[b * 65 + 64] = kE; off2[b * 65 + 64] = kE; }
    __syncthreads();
    if (t < kE) {
        int p = atomicAdd(&pos1[s1[b * kE + t]], 1); lst1[b * kE + p] = t;
        int q = atomicAdd(&pos2[s2[b * kE + t]], 1); lst2[b * kE + q] = t;
    }
}

// ---------------------------------------------------------------------------
// Edge class dedup (representative = min edge index sharing (s,d) key)
// ---------------------------------------------------------------------------
__global__ void edge_prep(const int* __restrict__ s1, const int* __restrict__ d1,
                          const int* __restrict__ s2, const int* __restrict__ d2,
                          int* __restrict__ map1, int* __restrict__ map2)
{
    int b = blockIdx.x, i = threadIdx.x;
    if (i < kE) {
        atomicMin(&map1[b * kNN + s1[b * kE + i] * kN + d1[b * kE + i]], i);
        atomicMin(&map2[b * kNN + s2[b * kE + i] * kN + d2[b * kE + i]], i);
    }
}

// Accumulate class-pair sums Sagg[b][rep1][rep2] += Ke[b][i][j]
__global__ __launch_bounds__(256) void sagg_k(
    const int* __restrict__ s1, const int* __restrict__ d1,
    const int* __restrict__ s2, const int* __restrict__ d2,
    const float* __restrict__ Ke, const int* __restrict__ map1,
    const int* __restrict__ map2, float* __restrict__ Sagg)
{
    int idx = blockIdx.x * 256 + threadIdx.x;      // 0 .. 8*192*192-1
    int b = idx / (kE * kE);
    int rem = idx - b * kE * kE;
    int i = rem / kE, j = rem - i * kE;
    int key1 = s1[b * kE + i] * kN + d1[b * kE + i];
    int key2 = s2[b * kE + j] * kN + d2[b * kE + j];
    int r1 = map1[b * kNN + key1];
    int r2 = map2[b * kNN + key2];
    atomicAdd(&Sagg[(size_t)b * kE * kE + r1 * kE + r2], Ke[idx]);
}

// Count positive off-diagonal accumulated entries per row (canonical pairs only)
__global__ __launch_bounds__(256) void deg_count(
    const int* __restrict__ s1, const int* __restrict__ d1,
    const int* __restrict__ s2, const int* __restrict__ d2,
    const float* __restrict__ Sagg, const int* __restrict__ map1,
    const int* __restrict__ map2, int* __restrict__ degcnt)
{
    int idx = blockIdx.x * 256 + threadIdx.x;
    int b = idx / (kE * kE);
    int rem = idx - b * kE * kE;
    int i = rem / kE, j = rem - i * kE;
    int a1 = s1[b * kE + i], c1 = d1[b * kE + i];
    int a2 = s2[b * kE + j], c2 = d2[b * kE + j];
    if (map1[b * kNN + a1 * kN + c1] != i) return;
    if (map2[b * kNN + a2 * kN + c2] != j) return;
    float val = Sagg[(size_t)b * kE * kE + i * kE + j];
    int r = a2 * kN + a1, c = c2 * kN + c1;
    if (r != c && val > 0.0f) atomicAdd(&degcnt[b * kNN + r], 1);
}

// deg = max(count + (Kdiag>0), 1);  kdiag[b][r] = Kp[b][r&63][r>>6]
__global__ __launch_bounds__(256) void deg_fin(const int* __restrict__ degcnt,
                                               const float* __restrict__ Kp,
                                               float* __restrict__ deg,
                                               float* __restrict__ kdiag)
{
    int idx = blockIdx.x * 256 + threadIdx.x;      // 0..32767
    int b = idx >> 12, r = idx & 4095;
    float kd = Kp[b * kNN + (r & 63) * kN + (r >> 6)];
    int d = degcnt[idx] + (kd > 0.0f ? 1 : 0);
    deg[idx] = fmaxf((float)d, 1.0f);
    kdiag[idx] = kd;
}

// ---------------------------------------------------------------------------
// Off-diagonal message via CSR GATHER (no atomics):
//   block (b, r2) computes msg[b, r2*64 + r1, c] for all r1, c:
//   msg = sum_{j in b2(r2)} sum_{i in b1(r1)} Ke[i,j] * x[d2[j]*64+d1[i], c]
//   excluding diagonal pairs (d2[j]==r2 && d1[i]==r1).
// Thread = r1*4 + cq; channels c = cq, cq+4, ...
// ---------------------------------------------------------------------------
template <int C>
__global__ __launch_bounds__(256) void msg_gather(
    const int* __restrict__ off1, const int* __restrict__ lst1,
    const int* __restrict__ off2, const int* __restrict__ lst2,
    const int* __restrict__ d1, const int* __restrict__ d2,
    const float* __restrict__ Ke, const float* __restrict__ x,
    float* __restrict__ msg)
{
    const int r2 = blockIdx.x, b = blockIdx.y;
    const int t = threadIdx.x;
    constexpr int NCH = (C + 3) / 4;   // channels per thread (max)

    __shared__ int jd2[kE];            // packed (j<<8)|d2[j]
    const int j0 = off2[b * 65 + r2], j1 = off2[b * 65 + r2 + 1];
    const int n2 = j1 - j0;
    for (int k = t; k < n2; k += 256) {
        int j = lst2[b * kE + j0 + k];
        jd2[k] = (j << 8) | d2[b * kE + j];
    }
    __syncthreads();

    const int r1 = t >> 2, cq = t & 3;
    const int i0 = off1[b * 65 + r1], i1 = off1[b * 65 + r1 + 1];

    float acc[NCH];
#pragma unroll
    for (int cc = 0; cc < NCH; ++cc) acc[cc] = 0.f;

    const float* Keb = Ke + (size_t)b * kE * kE;
    const float* xb  = x + (size_t)b * kNN * C;

    for (int k = 0; k < n2; ++k) {
        int pk = jd2[k];
        int j = pk >> 8, dd2 = pk & 255;
        const float* xrow = xb + (size_t)(dd2 * kN) * C;
        const float* kej  = Keb + j;
        for (int m = i0; m < i1; ++m) {
            int i = lst1[b * kE + m];
            int dd1 = d1[b * kE + i];
            if (dd2 == r2 && dd1 == r1) continue;   // diagonal overwritten later
            float kv = kej[(size_t)i * kE];
            const float* xc = xrow + dd1 * C;
#pragma unroll
            for (int cc = 0; cc < NCH; ++cc) {
                int c = cq + cc * 4;
                if (c < C) acc[cc] += kv * xc[c];
            }
        }
    }

    float* mr = msg + (size_t)(b * kNN + r2 * kN + r1) * C;
#pragma unroll
    for (int cc = 0; cc < NCH; ++cc) {
        int c = cq + cc * 4;
        if (c < C) mr[c] = acc[cc];
    }
}

// ---------------------------------------------------------------------------
// Per-row: add diagonal term, divide by deg, h = relu(m@W+b), v = h@S+c
// ---------------------------------------------------------------------------
template <int C>
__global__ __launch_bounds__(256) void layer_fuse(
    const float* __restrict__ msg, const float* __restrict__ x,
    const float* __restrict__ kdiag, const float* __restrict__ deg,
    const float* __restrict__ W, const float* __restrict__ bb,
    const float* __restrict__ S, const float* __restrict__ c0,
    float* __restrict__ xn, float* __restrict__ vbuf)
{
    int idx = blockIdx.x * 256 + threadIdx.x;      // b*4096 + r
    float kd = kdiag[idx];
    float dg = deg[idx];
    float m[C];
#pragma unroll
    for (int c = 0; c < C; ++c)
        m[c] = (msg[(size_t)idx * C + c] + kd * x[(size_t)idx * C + c]) / dg;
    float h[16];
#pragma unroll
    for (int f = 0; f < 16; ++f) {
        float a = bb[f];
#pragma unroll
        for (int c = 0; c < C; ++c) a += m[c] * W[c * 16 + f];
        h[f] = fmaxf(a, 0.f);
    }
    float v = c0[0];
#pragma unroll
    for (int f = 0; f < 16; ++f) {
        v += h[f] * S[f];
        xn[(size_t)idx * 17 + f] = h[f];
    }
    vbuf[idx] = v;
}

// ---------------------------------------------------------------------------
// Sinkhorn in LDS (one block per batch).
// ---------------------------------------------------------------------------
template <int NR, bool FINAL>
__global__ __launch_bounds__(320) void sinkhorn_k(const float* __restrict__ vin,
                                                  float* __restrict__ outp,
                                                  const float* __restrict__ binvp)
{
    constexpr int STRIDE = (NR % 2 == 0) ? NR + 1 : NR;
    __shared__ float mat[NR][STRIDE];
    const int b = blockIdx.x;
    const int tid = threadIdx.x;

    float binv = 0.f;
    if (FINAL) binv = binvp[0];

    for (int idx = tid; idx < NR * NR; idx += blockDim.x) {
        int p = idx / NR, q = idx - p * NR;
        float val;
        if (FINAL) {
            val = (p < kN && q < kN) ? vin[b * kNN + q * kN + p] : binv;
        } else {
            val = vin[b * kNN + q * kN + p] * kTauInv;
        }
        mat[p][q] = val;
    }
    __syncthreads();

    const int r = tid >> 2, s = tid & 3;
    const bool act = r < NR;

    for (int it = 0; it < 10; ++it) {
        float m = -1e30f;
        if (act) for (int q = s; q < NR; q += 4) m = fmaxf(m, mat[r][q]);
        m = fmaxf(m, __shfl_xor(m, 1));
        m = fmaxf(m, __shfl_xor(m, 2));
        float sum = 0.f;
        if (act) for (int q = s; q < NR; q += 4) sum += __expf(mat[r][q] - m);
        sum += __shfl_xor(sum, 1);
        sum += __shfl_xor(sum, 2);
        float lse = m + __logf(sum);
        if (act) for (int q = s; q < NR; q += 4) mat[r][q] -= lse;
        __syncthreads();
        m = -1e30f;
        if (act) for (int p = s; p < NR; p += 4) m = fmaxf(m, mat[p][r]);
        m = fmaxf(m, __shfl_xor(m, 1));
        m = fmaxf(m, __shfl_xor(m, 2));
        sum = 0.f;
        if (act) for (int p = s; p < NR; p += 4) sum += __expf(mat[p][r] - m);
        sum += __shfl_xor(sum, 1);
        sum += __shfl_xor(sum, 2);
        lse = m + __logf(sum);
        if (act) for (int p = s; p < NR; p += 4) mat[p][r] -= lse;
        __syncthreads();
    }

    for (int idx = tid; idx < NR * NR; idx += blockDim.x) {
        int p = idx / NR, q = idx - p * NR;
        float e = __expf(mat[p][q]);
        if (FINAL) {
            if (p < kN && q < kN) outp[((size_t)b * kN + p) * kN + q] = e;
        } else {
            outp[(size_t)(b * kNN + q * kN + p) * 17 + 16] = e;
        }
    }
}

// ---------------------------------------------------------------------------
__global__ __launch_bounds__(256) void final_proj(const float* __restrict__ x,
                                                  const float* __restrict__ Wc,
                                                  const float* __restrict__ bc,
                                                  float* __restrict__ vfin)
{
    int idx = blockIdx.x * 256 + threadIdx.x;
    float v = bc[0];
#pragma unroll
    for (int c = 0; c < 17; ++c) v += x[(size_t)idx * 17 + c] * Wc[c];
    vfin[idx] = v;
}

__global__ __launch_bounds__(256) void max_reduce(const float* __restrict__ outp,
                                                  unsigned* __restrict__ maxbuf)
{
    int idx = blockIdx.x * 256 + threadIdx.x;
    float v = outp[idx];
#pragma unroll
    for (int o = 32; o >= 1; o >>= 1) v = fmaxf(v, __shfl_xor(v, o));
    __shared__ float w[4];
    if ((threadIdx.x & 63) == 0) w[threadIdx.x >> 6] = v;
    __syncthreads();
    if (threadIdx.x == 0) {
        v = fmaxf(fmaxf(w[0], w[1]), fmaxf(w[2], w[3]));
        atomicMax(maxbuf, __float_as_uint(v));
    }
}

__global__ __launch_bounds__(256) void scale_out(float* __restrict__ outp,
                                                 const unsigned* __restrict__ maxbuf)
{
    int idx = blockIdx.x * 256 + threadIdx.x;
    outp[idx] = outp[idx] / __uint_as_float(maxbuf[0]);
}

// ---------------------------------------------------------------------------
extern "C" void kernel_launch(void* const* d_in, const int* in_sizes, int n_in,
                              void* d_out, int out_size, void* d_ws, size_t ws_size,
                              hipStream_t stream)
{
    (void)in_sizes; (void)n_in; (void)out_size; (void)ws_size;

    const float* x1    = (const float*)d_in[0];
    const float* x2    = (const float*)d_in[1];
    const float* e1    = (const float*)d_in[2];
    const float* e2    = (const float*)d_in[3];
    const float* Wp    = (const float*)d_in[4];
    const float* bp    = (const float*)d_in[5];
    const float* gamma = (const float*)d_in[6];
    const float* beta  = (const float*)d_in[7];
    const float* W0 = (const float*)d_in[8];
    const float* b0 = (const float*)d_in[9];
    const float* S0 = (const float*)d_in[10];
    const float* c0 = (const float*)d_in[11];
    const float* W1 = (const float*)d_in[12];
    const float* b1 = (const float*)d_in[13];
    const float* S1 = (const float*)d_in[14];
    const float* c1 = (const float*)d_in[15];
    const float* W2 = (const float*)d_in[16];
    const float* b2 = (const float*)d_in[17];
    const float* S2 = (const float*)d_in[18];
    const float* c2 = (const float*)d_in[19];
    const float* Wc = (const float*)d_in[20];
    const float* bc = (const float*)d_in[21];
    const float* binv = (const float*)d_in[22];
    const int* src1 = (const int*)d_in[23];
    const int* dst1 = (const int*)d_in[24];
    const int* src2 = (const int*)d_in[25];
    const int* dst2 = (const int*)d_in[26];

    float* out = (float*)d_out;
    float* wsf = (float*)d_ws;

    // workspace carve (floats)
    float* hbuf  = wsf;                    // 4096*256      = 1,048,576
    float* stats = hbuf + 1048576;         // 2048
    float* Kp    = stats + 2048;           // 8*64*64       = 32768
    float* Ke    = Kp + 32768;             // 8*192*192     = 294912
    float* Sagg  = Ke + 294912;            // 294912
    float* kdiag = Sagg + 294912;          // 32768  (also x0 / Kdiag)
    float* deg   = kdiag + 32768;          // 32768
    float* vbuf  = deg + 32768;            // 32768
    float* msg   = vbuf + 32768;           // 8*4096*17     = 557056
    float* xA    = msg + 557056;           // 557056
    float* xB    = xA + 557056;            // 557056
    int*   map1  = (int*)(xB + 557056);    // 32768
    int*   map2  = map1 + 32768;           // 32768
    int*   degcnt = map2 + 32768;          // 32768
    int*   off1  = degcnt + 32768;         // 8*65 = 520
    int*   off2  = off1 + 520;             // 520
    int*   lst1  = off2 + 520;             // 8*192 = 1536
    int*   lst2  = lst1 + 1536;            // 1536
    unsigned* maxbuf = (unsigned*)(lst2 + 1536);

    // zero/init the accumulation buffers
    hipMemsetAsync(stats, 0, 2048 * sizeof(float), stream);
    hipMemsetAsync(Sagg, 0, 294912 * sizeof(float), stream);
    hipMemsetAsync(map1, 0x7f, 2 * 32768 * sizeof(int), stream);  // map1+map2
    hipMemsetAsync(degcnt, 0, 32768 * sizeof(int), stream);
    hipMemsetAsync(maxbuf, 0, sizeof(unsigned), stream);

    // ---- projection + batchnorm + relu + l2norm ----
    gemm_proj<<<dim3(4, 64), 256, 0, stream>>>(x1, x2, e1, e2, Wp, bp, hbuf);
    bn_stats<<<dim3(8, 4), 256, 0, stream>>>(hbuf, stats);
    bn_fin<<<4, 256, 0, stream>>>(stats);
    bn_norm_l2<<<4096, 256, 0, stream>>>(hbuf, stats, gamma, beta);

    // ---- cosine similarity matrices ----
    gemm_nt<<<dim3(1, 1, 8), 256, 0, stream>>>(hbuf, hbuf + 512 * 256, Kp, 64, 64, 1.0f);
    gemm_nt<<<dim3(3, 3, 8), 256, 0, stream>>>(hbuf + 1024 * 256, hbuf + 2560 * 256, Ke, 192, 192, 0.5f);

    // ---- sparse K structure ----
    build_csr<<<8, 256, 0, stream>>>(src1, src2, off1, lst1, off2, lst2);
    edge_prep<<<8, 192, 0, stream>>>(src1, dst1, src2, dst2, map1, map2);
    sagg_k<<<1152, 256, 0, stream>>>(src1, dst1, src2, dst2, Ke, map1, map2, Sagg);
    deg_count<<<1152, 256, 0, stream>>>(src1, dst1, src2, dst2, Sagg, map1, map2, degcnt);
    deg_fin<<<128, 256, 0, stream>>>(degcnt, Kp, deg, kdiag);

    // ---- layer 0 (C=1, x = kdiag = Kp^T flattened) ----
    msg_gather<1><<<dim3(64, 8), 256, 0, stream>>>(off1, lst1, off2, lst2, dst1, dst2, Ke, kdiag, msg);
    layer_fuse<1><<<128, 256, 0, stream>>>(msg, kdiag, kdiag, deg, W0, b0, S0, c0, xA, vbuf);
    sinkhorn_k<64, false><<<8, 256, 0, stream>>>(vbuf, xA, nullptr);

    // ---- layer 1 (C=17) ----
    msg_gather<17><<<dim3(64, 8), 256, 0, stream>>>(off1, lst1, off2, lst2, dst1, dst2, Ke, xA, msg);
    layer_fuse<17><<<128, 256, 0, stream>>>(msg, xA, kdiag, deg, W1, b1, S1, c1, xB, vbuf);
    sinkhorn_k<64, false><<<8, 256, 0, stream>>>(vbuf, xB, nullptr);

    // ---- layer 2 (C=17) ----
    msg_gather<17><<<dim3(64, 8), 256, 0, stream>>>(off1, lst1, off2, lst2, dst1, dst2, Ke, xB, msg);
    layer_fuse<17><<<128, 256, 0, stream>>>(msg, xB, kdiag, deg, W2, b2, S2, c2, xA, vbuf);
    sinkhorn_k<64, false><<<8, 256, 0, stream>>>(vbuf, xA, nullptr);

    // ---- final projection + bin-augmented sinkhorn + global max normalize ----
    final_proj<<<128, 256, 0, stream>>>(xA, Wc, bc, vbuf);
    sinkhorn_k<65, true><<<8, 320, 0, stream>>>(vbuf, out, binv);
    max_reduce<<<128, 256, 0, stream>>>(out, maxbuf);
    scale_out<<<128, 256, 0, stream>>>(out, maxbuf);
}

// Round 3
// 435.376 us; speedup vs baseline: 2.6762x; 1.3785x over previous
//
#include <hip/hip_runtime.h>

constexpr int kB   = 8;
constexpr int kN   = 64;
constexpr int kE   = 192;
constexpr int kDin = 1024;
constexpr int kDp  = 256;
constexpr int kNN  = 4096;
constexpr float kTauInv = 20.0f;

// ---------------------------------------------------------------------------
// Projection GEMM, K-split (z) + double-buffered LDS, partial out (no bias).
// 64x64 tile, 256 threads, 4x4 micro-tile, K-chunk 16, one sync per chunk.
// ---------------------------------------------------------------------------
__global__ __launch_bounds__(256) void gemm_proj(
    const float* __restrict__ x1, const float* __restrict__ x2,
    const float* __restrict__ e1, const float* __restrict__ e2,
    const float* __restrict__ Wp, float* __restrict__ P)
{
    const int rt = blockIdx.y, ct = blockIdx.x, z = blockIdx.z;
    const int tid = threadIdx.x;
    const int tx = tid & 15, ty = tid >> 4;
    const int grow0 = rt * 64, col0 = ct * 64;

    const float* src; int lrow0;
    if (rt < 8)       { src = x1; lrow0 = grow0; }
    else if (rt < 16) { src = x2; lrow0 = grow0 - 512; }
    else if (rt < 40) { src = e1; lrow0 = grow0 - 1024; }
    else              { src = e2; lrow0 = grow0 - 2560; }

    __shared__ float As[2][16][68];
    __shared__ float Ws[2][16][68];

    const int arow = tid >> 2, acol = (tid & 3) * 4;
    const int wrow = tid >> 4, wcol = (tid & 15) * 4;

    const float* Abase = src + (size_t)(lrow0 + arow) * kDin + z * 512 + acol;
    const float* Wbase = Wp + (size_t)(z * 512 + wrow) * kDp + col0 + wcol;

    float4 a4 = *(const float4*)Abase;
    float4 w4 = *(const float4*)Wbase;

    float acc[4][4] = {};

    for (int c = 0; c < 32; ++c) {
        const int cur = c & 1;
        As[cur][acol + 0][arow] = a4.x;
        As[cur][acol + 1][arow] = a4.y;
        As[cur][acol + 2][arow] = a4.z;
        As[cur][acol + 3][arow] = a4.w;
        *(float4*)&Ws[cur][wrow][wcol] = w4;
        __syncthreads();
        if (c < 31) {
            a4 = *(const float4*)(Abase + (c + 1) * 16);
            w4 = *(const float4*)(Wbase + (size_t)(c + 1) * 16 * kDp);
        }
#pragma unroll
        for (int kk = 0; kk < 16; ++kk) {
            float4 av = *(const float4*)&As[cur][kk][ty * 4];
            float4 wv = *(const float4*)&Ws[cur][kk][tx * 4];
            float a[4] = {av.x, av.y, av.z, av.w};
            float w[4] = {wv.x, wv.y, wv.z, wv.w};
#pragma unroll
            for (int i = 0; i < 4; ++i)
#pragma unroll
                for (int j = 0; j < 4; ++j)
                    acc[i][j] += a[i] * w[j];
        }
    }
    float* Pz = P + (size_t)z * 1048576;
#pragma unroll
    for (int i = 0; i < 4; ++i)
#pragma unroll
        for (int j = 0; j < 4; ++j)
            Pz[(size_t)(grow0 + ty * 4 + i) * kDp + col0 + tx * 4 + j] = acc[i][j];
}

// hbuf = P0 + P1 + bias (float4)
__global__ __launch_bounds__(256) void reduce_bias(const float* __restrict__ P,
                                                   const float* __restrict__ bp,
                                                   float* __restrict__ hbuf)
{
    int idx = blockIdx.x * 256 + threadIdx.x;           // float4 index, 262144
    float4 p0 = ((const float4*)P)[idx];
    float4 p1 = ((const float4*)(P + 1048576))[idx];
    float4 bb = ((const float4*)bp)[idx & 63];
    float4 r;
    r.x = p0.x + p1.x + bb.x; r.y = p0.y + p1.y + bb.y;
    r.z = p0.z + p1.z + bb.z; r.w = p0.w + p1.w + bb.w;
    ((float4*)hbuf)[idx] = r;
}

// ---------------------------------------------------------------------------
// BatchNorm stats / finalize / normalize+relu+l2 (unchanged, verified R1-R2)
// ---------------------------------------------------------------------------
__global__ __launch_bounds__(256) void bn_stats(const float* __restrict__ hbuf,
                                                float* __restrict__ stats)
{
    int seg = blockIdx.y, chunk = blockIdx.x, tid = threadIdx.x;
    int start = (seg == 0) ? 0 : (seg == 1 ? 512 : (seg == 2 ? 1024 : 2560));
    int len   = (seg < 2) ? 512 : 1536;
    int rows  = len >> 3;
    int r0 = start + chunk * rows;
    float s = 0.f, s2 = 0.f;
    for (int r = 0; r < rows; ++r) {
        float v = hbuf[(size_t)(r0 + r) * kDp + tid];
        s += v; s2 += v * v;
    }
    atomicAdd(&stats[seg * 512 + tid], s);
    atomicAdd(&stats[seg * 512 + 256 + tid], s2);
}

__global__ void bn_fin(float* stats)
{
    int seg = blockIdx.x, tid = threadIdx.x;
    float n = (seg < 2) ? 512.f : 1536.f;
    float mu  = stats[seg * 512 + tid] / n;
    float var = stats[seg * 512 + 256 + tid] / n - mu * mu;
    stats[seg * 512 + tid] = mu;
    stats[seg * 512 + 256 + tid] = rsqrtf(var + 1e-5f);
}

__global__ __launch_bounds__(256) void bn_norm_l2(float* hbuf,
                                                  const float* __restrict__ stats,
                                                  const float* __restrict__ gamma,
                                                  const float* __restrict__ beta)
{
    int r = blockIdx.x, tid = threadIdx.x;
    int seg = (r < 512) ? 0 : (r < 1024 ? 1 : (r < 2560 ? 2 : 3));
    float mu   = stats[seg * 512 + tid];
    float istd = stats[seg * 512 + 256 + tid];
    float v = hbuf[(size_t)r * kDp + tid];
    float p = fmaxf((v - mu) * istd * gamma[tid] + beta[tid], 0.f);
    float ss = p * p;
#pragma unroll
    for (int o = 32; o >= 1; o >>= 1) ss += __shfl_xor(ss, o);
    __shared__ float wsum[4];
    if ((tid & 63) == 0) wsum[tid >> 6] = ss;
    __syncthreads();
    float tot = wsum[0] + wsum[1] + wsum[2] + wsum[3];
    float scale = 1.f / fmaxf(sqrtf(tot), 1e-12f);
    hbuf[(size_t)r * kDp + tid] = p * scale;
}

// ---------------------------------------------------------------------------
// Combined similarity GEMMs: Kp (64x64, x1) and Ke (0.5, 192x192) per batch.
// 32x32 tiles, K=256 in chunks of 32. 40 tiles/batch -> 320 blocks.
// ---------------------------------------------------------------------------
__global__ __launch_bounds__(256) void gemm_sim(const float* __restrict__ hbuf,
                                                float* __restrict__ Kp,
                                                float* __restrict__ Ke)
{
    const int id = blockIdx.x, b = blockIdx.y, t = threadIdx.x;
    int mt, nt, ldo; const float *X, *Y; float* outp; float scale;
    if (id < 4) {
        mt = (id >> 1) * 32; nt = (id & 1) * 32; ldo = 64;
        X = hbuf + (size_t)b * 64 * kDp;
        Y = hbuf + (512 + (size_t)b * 64) * kDp;
        outp = Kp + (size_t)b * 4096; scale = 1.0f;
    } else {
        int e = id - 4;
        mt = (e / 6) * 32; nt = (e % 6) * 32; ldo = 192;
        X = hbuf + (1024 + (size_t)b * 192) * kDp;
        Y = hbuf + (2560 + (size_t)b * 192) * kDp;
        outp = Ke + (size_t)b * 36864; scale = 0.5f;
    }
    __shared__ float Xs[32][36];
    __shared__ float Ys[32][36];
    const int row = t >> 3, kq = t & 7;
    const int ty = t >> 4, tx = t & 15;
    float acc[2][2] = {};
    for (int k0 = 0; k0 < kDp; k0 += 32) {
        float4 xa = *(const float4*)(X + (size_t)(mt + row) * kDp + k0 + kq * 4);
        float4 ya = *(const float4*)(Y + (size_t)(nt + row) * kDp + k0 + kq * 4);
        Xs[kq * 4 + 0][row] = xa.x; Xs[kq * 4 + 1][row] = xa.y;
        Xs[kq * 4 + 2][row] = xa.z; Xs[kq * 4 + 3][row] = xa.w;
        Ys[kq * 4 + 0][row] = ya.x; Ys[kq * 4 + 1][row] = ya.y;
        Ys[kq * 4 + 2][row] = ya.z; Ys[kq * 4 + 3][row] = ya.w;
        __syncthreads();
#pragma unroll
        for (int kk = 0; kk < 32; ++kk) {
            float2 xv = *(const float2*)&Xs[kk][ty * 2];
            float2 yv = *(const float2*)&Ys[kk][tx * 2];
            acc[0][0] += xv.x * yv.x; acc[0][1] += xv.x * yv.y;
            acc[1][0] += xv.y * yv.x; acc[1][1] += xv.y * yv.y;
        }
        __syncthreads();
    }
#pragma unroll
    for (int i = 0; i < 2; ++i)
#pragma unroll
        for (int j = 0; j < 2; ++j)
            outp[(size_t)(mt + ty * 2 + i) * ldo + nt + tx * 2 + j] = scale * acc[i][j];
}

// ---------------------------------------------------------------------------
// Per-batch CSR bucket by source node (verified R2)
// ---------------------------------------------------------------------------
__global__ __launch_bounds__(256) void build_csr(
    const int* __restrict__ s1, const int* __restrict__ s2,
    int* __restrict__ off1, int* __restrict__ lst1,
    int* __restrict__ off2, int* __restrict__ lst2)
{
    int b = blockIdx.x, t = threadIdx.x;
    __shared__ int cnt1[64], cnt2[64], pos1[64], pos2[64];
    if (t < 64) { cnt1[t] = 0; cnt2[t] = 0; }
    __syncthreads();
    if (t < kE) {
        atomicAdd(&cnt1[s1[b * kE + t]], 1);
        atomicAdd(&cnt2[s2[b * kE + t]], 1);
    }
    __syncthreads();
    if (t == 0) {
        int a = 0, c = 0;
        for (int v = 0; v < 64; ++v) {
            pos1[v] = a; a += cnt1[v];
            pos2[v] = c; c += cnt2[v];
        }
    }
    __syncthreads();
    if (t < 64) { off1[b * 65 + t] = pos1[t]; off2[b * 65 + t] = pos2[t]; }
    if (t == 0) { off1[b * 65 + 64] = kE; off2[b * 65 + 64] = kE; }
    __syncthreads();
    if (t < kE) {
        int p = atomicAdd(&pos1[s1[b * kE + t]], 1); lst1[b * kE + p] = t;
        int q = atomicAdd(&pos2[s2[b * kE + t]], 1); lst2[b * kE + q] = t;
    }
}

// ---------------------------------------------------------------------------
// Sparse-K degree pipeline, all in LDS. Block (third t3, batch b):
// owns Sagg rows rep1 in [t3*64, t3*64+64). Computes class reps in-LDS,
// accumulates class-pair sums (LDS f32 atomics), counts positive off-diag
// entries (packed 16-bit LDS counts), merges into global degcnt.
// ---------------------------------------------------------------------------
__global__ __launch_bounds__(256) void ksparse(
    const int* __restrict__ s1, const int* __restrict__ d1,
    const int* __restrict__ s2, const int* __restrict__ d2,
    const float* __restrict__ Ke, int* __restrict__ degcnt)
{
    const int t3 = blockIdx.x, b = blockIdx.y, t = threadIdx.x;
    __shared__ float SaggL[64][192];     // 48 KB
    __shared__ int   cnt2p[2048];        // 8 KB, 2x16-bit counts
    __shared__ short es1[kE], ed1[kE], es2[kE], ed2[kE];
    __shared__ short rep1[kE], rep2[kE];
    __shared__ short myi[kE];
    __shared__ int mycnt;

    for (int i = t; i < kE; i += 256) {
        es1[i] = (short)s1[b * kE + i]; ed1[i] = (short)d1[b * kE + i];
        es2[i] = (short)s2[b * kE + i]; ed2[i] = (short)d2[b * kE + i];
    }
    for (int i = t; i < 64 * 192; i += 256) ((float*)SaggL)[i] = 0.f;
    for (int i = t; i < 2048; i += 256) cnt2p[i] = 0;
    if (t == 0) mycnt = 0;
    __syncthreads();

    // class representatives (first index with matching key == min)
    for (int i = t; i < kE; i += 256) {
        int k1 = es1[i] * 64 + ed1[i], k2 = es2[i] * 64 + ed2[i];
        int r1 = i, r2 = i;
        for (int i2 = 0; i2 < kE; ++i2) {
            if (es1[i2] * 64 + ed1[i2] == k1) { r1 = i2; break; }
        }
        for (int i2 = 0; i2 < kE; ++i2) {
            if (es2[i2] * 64 + ed2[i2] == k2) { r2 = i2; break; }
        }
        rep1[i] = (short)r1; rep2[i] = (short)r2;
        if ((r1 >> 6) == t3) {
            int p = atomicAdd(&mycnt, 1);
            myi[p] = (short)i;
        }
    }
    __syncthreads();

    const int nm = mycnt;
    const float* Keb = Ke + (size_t)b * kE * kE;

    // accumulate class-pair sums for owned rows
    for (int idx = t; idx < nm * kE; idx += 256) {
        int ii = idx / kE, j = idx - ii * kE;
        int i = myi[ii];
        atomicAdd(&SaggL[rep1[i] - t3 * 64][rep2[j]], Keb[(size_t)i * kE + j]);
    }
    __syncthreads();

    // count positive off-diagonal canonical entries
    for (int idx = t; idx < nm * kE; idx += 256) {
        int ii = idx / kE, j = idx - ii * kE;
        int i = myi[ii];
        if (rep1[i] != i || rep2[j] != j) continue;
        float val = SaggL[i - t3 * 64][j];
        int r = es2[j] * 64 + es1[i];
        int c = ed2[j] * 64 + ed1[i];
        if (r != c && val > 0.0f)
            atomicAdd(&cnt2p[r >> 1], 1 << ((r & 1) * 16));
    }
    __syncthreads();

    // merge into global
    for (int r = t; r < kNN; r += 256) {
        int cv = (cnt2p[r >> 1] >> ((r & 1) * 16)) & 0xffff;
        if (cv) atomicAdd(&degcnt[b * kNN + r], cv);
    }
}

__global__ __launch_bounds__(256) void deg_fin(const int* __restrict__ degcnt,
                                               const float* __restrict__ Kp,
                                               float* __restrict__ deg,
                                               float* __restrict__ kdiag)
{
    int idx = blockIdx.x * 256 + threadIdx.x;
    int b = idx >> 12, r = idx & 4095;
    float kd = Kp[b * kNN + (r & 63) * kN + (r >> 6)];
    int d = degcnt[idx] + (kd > 0.0f ? 1 : 0);
    deg[idx] = fmaxf((float)d, 1.0f);
    kdiag[idx] = kd;
}

// ---------------------------------------------------------------------------
// Fused message-gather + layer MLP. Block (r2, b), 256 threads (4 per row).
// Gather msg into LDS tile, then h = relu(m@W+b) -> xn[0:16], v = h@S+c -> vbuf.
// ---------------------------------------------------------------------------
template <int C>
__global__ __launch_bounds__(256) void layer_k(
    const int* __restrict__ off1, const int* __restrict__ lst1,
    const int* __restrict__ off2, const int* __restrict__ lst2,
    const int* __restrict__ d1, const int* __restrict__ d2,
    const float* __restrict__ Ke, const float* __restrict__ x,
    const float* __restrict__ kdiag, const float* __restrict__ deg,
    const float* __restrict__ W, const float* __restrict__ bb,
    const float* __restrict__ S, const float* __restrict__ c0,
    float* __restrict__ xn, float* __restrict__ vbuf)
{
    const int r2 = blockIdx.x, b = blockIdx.y, t = threadIdx.x;
    __shared__ float WL[C * 16];
    __shared__ float bL[16], SL[16];
    __shared__ float c0v;
    __shared__ int jd2[kE];            // (j<<8)|d2[j]
    __shared__ int il[kE];             // (i<<8)|d1[i], CSR order
    __shared__ float msgT[64][18];

    for (int k = t; k < C * 16; k += 256) WL[k] = W[k];
    if (t < 16) { bL[t] = bb[t]; SL[t] = S[t]; }
    if (t == 0) c0v = c0[0];
    const int j0 = off2[b * 65 + r2];
    const int n2 = off2[b * 65 + r2 + 1] - j0;
    for (int k = t; k < n2; k += 256) {
        int j = lst2[b * kE + j0 + k];
        jd2[k] = (j << 8) | d2[b * kE + j];
    }
    for (int k = t; k < kE; k += 256) {
        int i = lst1[b * kE + k];
        il[k] = (i << 8) | d1[b * kE + i];
    }
    __syncthreads();

    const int r1 = t >> 2, lane = t & 3;
    const int i0 = off1[b * 65 + r1], i1 = off1[b * 65 + r1 + 1];
    const float* Keb = Ke + (size_t)b * kE * kE;
    const float* xb  = x + (size_t)b * kNN * C;

    if (C == 1) {
        float acc = 0.f;
        for (int k = 0; k < n2; ++k) {
            int pk = jd2[k], j = pk >> 8, dd2 = pk & 255;
            const float* xrow = xb + dd2 * 64;
            for (int m = i0 + lane; m < i1; m += 4) {
                int pi = il[m], i = pi >> 8, dd1 = pi & 255;
                if (dd2 == r2 && dd1 == r1) continue;
                acc += Keb[(size_t)i * kE + j] * xrow[dd1];
            }
        }
        acc += __shfl_xor(acc, 1);
        acc += __shfl_xor(acc, 2);
        if (lane == 0) msgT[r1][0] = acc;
    } else {
        constexpr int NCH = (C + 3) / 4;
        float acc[NCH];
#pragma unroll
        for (int cc = 0; cc < NCH; ++cc) acc[cc] = 0.f;
        for (int k = 0; k < n2; ++k) {
            int pk = jd2[k], j = pk >> 8, dd2 = pk & 255;
            const float* xrow = xb + (size_t)(dd2 * 64) * C;
            for (int m = i0; m < i1; ++m) {
                int pi = il[m], i = pi >> 8, dd1 = pi & 255;
                if (dd2 == r2 && dd1 == r1) continue;
                float kv = Keb[(size_t)i * kE + j];
                const float* xc = xrow + dd1 * C;
#pragma unroll
                for (int cc = 0; cc < NCH; ++cc) {
                    int c = lane + cc * 4;
                    if (c < C) acc[cc] += kv * xc[c];
                }
            }
        }
#pragma unroll
        for (int cc = 0; cc < NCH; ++cc) {
            int c = lane + cc * 4;
            if (c < C) msgT[r1][c] = acc[cc];
        }
    }
    __syncthreads();

    // compute phase: thread (r1, lane) -> h[lane*4 .. lane*4+3]
    const int row = r2 * 64 + r1;
    const int idx = b * kNN + row;
    const float kd = kdiag[idx];
    const float dg = deg[idx];
    float m[C];
#pragma unroll
    for (int c = 0; c < C; ++c)
        m[c] = (msgT[r1][c] + kd * xb[(size_t)row * C + c]) / dg;
    float vpart = 0.f;
#pragma unroll
    for (int ff = 0; ff < 4; ++ff) {
        int f = lane * 4 + ff;
        float a = bL[f];
#pragma unroll
        for (int c = 0; c < C; ++c) a += m[c] * WL[c * 16 + f];
        float h = fmaxf(a, 0.f);
        xn[(size_t)idx * 17 + f] = h;
        vpart += h * SL[f];
    }
    vpart += __shfl_xor(vpart, 1);
    vpart += __shfl_xor(vpart, 2);
    if (lane == 0) vbuf[idx] = vpart + c0v;
}

// ---------------------------------------------------------------------------
// Sinkhorn, 8 lanes per row, register-cached values, stride-68 LDS.
// FINAL fuses the last projection (x@Wc+bc) into the load.
// ---------------------------------------------------------------------------
template <int NR, int THREADS, bool FINAL>
__global__ __launch_bounds__(THREADS) void sinkhorn_k(
    const float* __restrict__ vin, float* __restrict__ outp,
    const float* __restrict__ binvp, const float* __restrict__ Wc,
    const float* __restrict__ bc)
{
    __shared__ float mat[NR][68];
    __shared__ float WcL[17];
    __shared__ float bcv, binvv;
    const int b = blockIdx.x, tid = threadIdx.x;

    if (FINAL) {
        if (tid < 17) WcL[tid] = Wc[tid];
        if (tid == 17) bcv = bc[0];
        if (tid == 18) binvv = binvp[0];
        __syncthreads();
    }
    for (int idx = tid; idx < NR * NR; idx += THREADS) {
        int q = idx / NR, p = idx - q * NR;
        float val;
        if (FINAL) {
            if (p < kN && q < kN) {
                const float* xr = vin + (size_t)(b * kNN + q * kN + p) * 17;
                float v = bcv;
#pragma unroll
                for (int c = 0; c < 17; ++c) v += xr[c] * WcL[c];
                val = v;
            } else val = binvv;
        } else {
            val = vin[b * kNN + q * kN + p] * kTauInv;
        }
        mat[p][q] = val;
    }
    __syncthreads();

    const int r = tid >> 3, s = tid & 7;
    const bool act = r < NR;
    const int cnt = act ? ((NR - s + 7) >> 3) : 0;
    float vals[(NR + 7) / 8];

    for (int it = 0; it < 10; ++it) {
        // normalize rows (axis 2)
        float mx = -1e30f;
        for (int k = 0; k < cnt; ++k) { vals[k] = mat[r][s + 8 * k]; mx = fmaxf(mx, vals[k]); }
        mx = fmaxf(mx, __shfl_xor(mx, 1));
        mx = fmaxf(mx, __shfl_xor(mx, 2));
        mx = fmaxf(mx, __shfl_xor(mx, 4));
        float sum = 0.f;
        for (int k = 0; k < cnt; ++k) sum += __expf(vals[k] - mx);
        sum += __shfl_xor(sum, 1);
        sum += __shfl_xor(sum, 2);
        sum += __shfl_xor(sum, 4);
        float lse = mx + __logf(sum);
        for (int k = 0; k < cnt; ++k) mat[r][s + 8 * k] = vals[k] - lse;
        __syncthreads();
        // normalize cols (axis 1)
        mx = -1e30f;
        for (int k = 0; k < cnt; ++k) { vals[k] = mat[s + 8 * k][r]; mx = fmaxf(mx, vals[k]); }
        mx = fmaxf(mx, __shfl_xor(mx, 1));
        mx = fmaxf(mx, __shfl_xor(mx, 2));
        mx = fmaxf(mx, __shfl_xor(mx, 4));
        sum = 0.f;
        for (int k = 0; k < cnt; ++k) sum += __expf(vals[k] - mx);
        sum += __shfl_xor(sum, 1);
        sum += __shfl_xor(sum, 2);
        sum += __shfl_xor(sum, 4);
        lse = mx + __logf(sum);
        for (int k = 0; k < cnt; ++k) mat[s + 8 * k][r] = vals[k] - lse;
        __syncthreads();
    }

    for (int idx = tid; idx < NR * NR; idx += THREADS) {
        int q = idx / NR, p = idx - q * NR;
        float e = __expf(mat[p][q]);
        if (FINAL) {
            if (p < kN && q < kN) outp[((size_t)b * kN + p) * kN + q] = e;
        } else {
            outp[(size_t)(b * kNN + q * kN + p) * 17 + 16] = e;
        }
    }
}

__global__ __launch_bounds__(256) void max_reduce(const float* __restrict__ outp,
                                                  unsigned* __restrict__ maxbuf)
{
    int idx = blockIdx.x * 256 + threadIdx.x;
    float v = outp[idx];
#pragma unroll
    for (int o = 32; o >= 1; o >>= 1) v = fmaxf(v, __shfl_xor(v, o));
    __shared__ float w[4];
    if ((threadIdx.x & 63) == 0) w[threadIdx.x >> 6] = v;
    __syncthreads();
    if (threadIdx.x == 0) {
        v = fmaxf(fmaxf(w[0], w[1]), fmaxf(w[2], w[3]));
        atomicMax(maxbuf, __float_as_uint(v));
    }
}

__global__ __launch_bounds__(256) void scale_out(float* __restrict__ outp,
                                                 const unsigned* __restrict__ maxbuf)
{
    int idx = blockIdx.x * 256 + threadIdx.x;
    outp[idx] = outp[idx] / __uint_as_float(maxbuf[0]);
}

// ---------------------------------------------------------------------------
extern "C" void kernel_launch(void* const* d_in, const int* in_sizes, int n_in,
                              void* d_out, int out_size, void* d_ws, size_t ws_size,
                              hipStream_t stream)
{
    (void)in_sizes; (void)n_in; (void)out_size; (void)ws_size;

    const float* x1    = (const float*)d_in[0];
    const float* x2    = (const float*)d_in[1];
    const float* e1    = (const float*)d_in[2];
    const float* e2    = (const float*)d_in[3];
    const float* Wp    = (const float*)d_in[4];
    const float* bp    = (const float*)d_in[5];
    const float* gamma = (const float*)d_in[6];
    const float* beta  = (const float*)d_in[7];
    const float* W0 = (const float*)d_in[8];
    const float* b0 = (const float*)d_in[9];
    const float* S0 = (const float*)d_in[10];
    const float* c0 = (const float*)d_in[11];
    const float* W1 = (const float*)d_in[12];
    const float* b1 = (const float*)d_in[13];
    const float* S1 = (const float*)d_in[14];
    const float* c1 = (const float*)d_in[15];
    const float* W2 = (const float*)d_in[16];
    const float* b2 = (const float*)d_in[17];
    const float* S2 = (const float*)d_in[18];
    const float* c2 = (const float*)d_in[19];
    const float* Wc = (const float*)d_in[20];
    const float* bc = (const float*)d_in[21];
    const float* binv = (const float*)d_in[22];
    const int* src1 = (const int*)d_in[23];
    const int* dst1 = (const int*)d_in[24];
    const int* src2 = (const int*)d_in[25];
    const int* dst2 = (const int*)d_in[26];

    float* out = (float*)d_out;
    float* wsf = (float*)d_ws;

    // workspace carve (floats).  P (2x1M partials) overlays everything below
    // Kp..lst2 — safe because those are written only after reduce_bias.
    float* hbuf  = wsf;                    // 1,048,576
    float* P     = hbuf + 1048576;         // 2,097,152 (transient)
    float* Kp    = P;                      // 32768
    float* Ke    = Kp + 32768;             // 294912
    float* kdiag = Ke + 294912;            // 32768
    float* deg   = kdiag + 32768;          // 32768
    float* vbuf  = deg + 32768;            // 32768
    float* xA    = vbuf + 32768;           // 557056
    float* xB    = xA + 557056;            // 557056
    float* stats = xB + 557056;            // 2048
    int*   degcnt = (int*)(stats + 2048);  // 32768
    unsigned* maxbuf = (unsigned*)(degcnt + 32768); // 1
    int*   off1 = (int*)(maxbuf + 1);      // 520
    int*   off2 = off1 + 520;              // 520
    int*   lst1 = off2 + 520;              // 1536
    int*   lst2 = lst1 + 1536;             // 1536

    // ---- projection GEMM (K-split) + reduce ----
    gemm_proj<<<dim3(4, 64, 2), 256, 0, stream>>>(x1, x2, e1, e2, Wp, P);
    reduce_bias<<<1024, 256, 0, stream>>>(P, bp, hbuf);

    // zero stats + degcnt + maxbuf (contiguous) — after P is dead
    hipMemsetAsync(stats, 0, (2048 + 32768 + 1) * sizeof(float), stream);

    // ---- batchnorm + relu + l2norm ----
    bn_stats<<<dim3(8, 4), 256, 0, stream>>>(hbuf, stats);
    bn_fin<<<4, 256, 0, stream>>>(stats);
    bn_norm_l2<<<4096, 256, 0, stream>>>(hbuf, stats, gamma, beta);

    // ---- similarity GEMMs (one dispatch) ----
    gemm_sim<<<dim3(40, 8), 256, 0, stream>>>(hbuf, Kp, Ke);

    // ---- sparse K structure ----
    build_csr<<<8, 256, 0, stream>>>(src1, src2, off1, lst1, off2, lst2);
    ksparse<<<dim3(3, 8), 256, 0, stream>>>(src1, dst1, src2, dst2, Ke, degcnt);
    deg_fin<<<128, 256, 0, stream>>>(degcnt, Kp, deg, kdiag);

    // ---- GNN layers (fused gather+MLP) + sinkhorns ----
    layer_k<1><<<dim3(64, 8), 256, 0, stream>>>(off1, lst1, off2, lst2, dst1, dst2,
                                                Ke, kdiag, kdiag, deg, W0, b0, S0, c0, xA, vbuf);
    sinkhorn_k<64, 512, false><<<8, 512, 0, stream>>>(vbuf, xA, nullptr, nullptr, nullptr);

    layer_k<17><<<dim3(64, 8), 256, 0, stream>>>(off1, lst1, off2, lst2, dst1, dst2,
                                                 Ke, xA, kdiag, deg, W1, b1, S1, c1, xB, vbuf);
    sinkhorn_k<64, 512, false><<<8, 512, 0, stream>>>(vbuf, xB, nullptr, nullptr, nullptr);

    layer_k<17><<<dim3(64, 8), 256, 0, stream>>>(off1, lst1, off2, lst2, dst1, dst2,
                                                 Ke, xB, kdiag, deg, W2, b2, S2, c2, xA, vbuf);
    sinkhorn_k<64, 512, false><<<8, 512, 0, stream>>>(vbuf, xA, nullptr, nullptr, nullptr);

    // ---- final: fused projection + bin-augmented sinkhorn + normalize ----
    sinkhorn_k<65, 576, true><<<8, 576, 0, stream>>>(xA, out, binv, Wc, bc);
    max_reduce<<<128, 256, 0, stream>>>(out, maxbuf);
    scale_out<<<128, 256, 0, stream>>>(out, maxbuf);
}

// Round 4
// 402.355 us; speedup vs baseline: 2.8958x; 1.0821x over previous
//
#include <hip/hip_runtime.h>

constexpr int kB   = 8;
constexpr int kN   = 64;
constexpr int kE   = 192;
constexpr int kDin = 1024;
constexpr int kDp  = 256;
constexpr int kNN  = 4096;
constexpr float kTauInv = 20.0f;

// ---------------------------------------------------------------------------
// Projection GEMM, K-split (z=2) + double-buffered LDS, partial out (no bias).
// ---------------------------------------------------------------------------
__global__ __launch_bounds__(256) void gemm_proj(
    const float* __restrict__ x1, const float* __restrict__ x2,
    const float* __restrict__ e1, const float* __restrict__ e2,
    const float* __restrict__ Wp, float* __restrict__ P)
{
    const int rt = blockIdx.y, ct = blockIdx.x, z = blockIdx.z;
    const int tid = threadIdx.x;
    const int tx = tid & 15, ty = tid >> 4;
    const int grow0 = rt * 64, col0 = ct * 64;

    const float* src; int lrow0;
    if (rt < 8)       { src = x1; lrow0 = grow0; }
    else if (rt < 16) { src = x2; lrow0 = grow0 - 512; }
    else if (rt < 40) { src = e1; lrow0 = grow0 - 1024; }
    else              { src = e2; lrow0 = grow0 - 2560; }

    __shared__ float As[2][16][68];
    __shared__ float Ws[2][16][68];

    const int arow = tid >> 2, acol = (tid & 3) * 4;
    const int wrow = tid >> 4, wcol = (tid & 15) * 4;

    const float* Abase = src + (size_t)(lrow0 + arow) * kDin + z * 512 + acol;
    const float* Wbase = Wp + (size_t)(z * 512 + wrow) * kDp + col0 + wcol;

    float4 a4 = *(const float4*)Abase;
    float4 w4 = *(const float4*)Wbase;

    float acc[4][4] = {};

    for (int c = 0; c < 32; ++c) {
        const int cur = c & 1;
        As[cur][acol + 0][arow] = a4.x;
        As[cur][acol + 1][arow] = a4.y;
        As[cur][acol + 2][arow] = a4.z;
        As[cur][acol + 3][arow] = a4.w;
        *(float4*)&Ws[cur][wrow][wcol] = w4;
        __syncthreads();
        if (c < 31) {
            a4 = *(const float4*)(Abase + (c + 1) * 16);
            w4 = *(const float4*)(Wbase + (size_t)(c + 1) * 16 * kDp);
        }
#pragma unroll
        for (int kk = 0; kk < 16; ++kk) {
            float4 av = *(const float4*)&As[cur][kk][ty * 4];
            float4 wv = *(const float4*)&Ws[cur][kk][tx * 4];
            float a[4] = {av.x, av.y, av.z, av.w};
            float w[4] = {wv.x, wv.y, wv.z, wv.w};
#pragma unroll
            for (int i = 0; i < 4; ++i)
#pragma unroll
                for (int j = 0; j < 4; ++j)
                    acc[i][j] += a[i] * w[j];
        }
    }
    float* Pz = P + (size_t)z * 1048576;
#pragma unroll
    for (int i = 0; i < 4; ++i)
#pragma unroll
        for (int j = 0; j < 4; ++j)
            Pz[(size_t)(grow0 + ty * 4 + i) * kDp + col0 + tx * 4 + j] = acc[i][j];
}

__global__ __launch_bounds__(256) void reduce_bias(const float* __restrict__ P,
                                                   const float* __restrict__ bp,
                                                   float* __restrict__ hbuf)
{
    int idx = blockIdx.x * 256 + threadIdx.x;
    float4 p0 = ((const float4*)P)[idx];
    float4 p1 = ((const float4*)(P + 1048576))[idx];
    float4 bb = ((const float4*)bp)[idx & 63];
    float4 r;
    r.x = p0.x + p1.x + bb.x; r.y = p0.y + p1.y + bb.y;
    r.z = p0.z + p1.z + bb.z; r.w = p0.w + p1.w + bb.w;
    ((float4*)hbuf)[idx] = r;
}

// ---------------------------------------------------------------------------
// BatchNorm stats + normalize+relu+l2 (bn_fin folded into bn_norm_l2)
// ---------------------------------------------------------------------------
__global__ __launch_bounds__(256) void bn_stats(const float* __restrict__ hbuf,
                                                float* __restrict__ stats)
{
    int seg = blockIdx.y, chunk = blockIdx.x, tid = threadIdx.x;
    int start = (seg == 0) ? 0 : (seg == 1 ? 512 : (seg == 2 ? 1024 : 2560));
    int len   = (seg < 2) ? 512 : 1536;
    int rows  = len >> 3;
    int r0 = start + chunk * rows;
    float s = 0.f, s2 = 0.f;
    for (int r = 0; r < rows; ++r) {
        float v = hbuf[(size_t)(r0 + r) * kDp + tid];
        s += v; s2 += v * v;
    }
    atomicAdd(&stats[seg * 512 + tid], s);
    atomicAdd(&stats[seg * 512 + 256 + tid], s2);
}

__global__ __launch_bounds__(256) void bn_norm_l2(float* hbuf,
                                                  const float* __restrict__ stats,
                                                  const float* __restrict__ gamma,
                                                  const float* __restrict__ beta)
{
    int r = blockIdx.x, tid = threadIdx.x;
    int seg = (r < 512) ? 0 : (r < 1024 ? 1 : (r < 2560 ? 2 : 3));
    float n = (seg < 2) ? 512.f : 1536.f;
    float mu   = stats[seg * 512 + tid] / n;
    float var  = stats[seg * 512 + 256 + tid] / n - mu * mu;
    float istd = rsqrtf(var + 1e-5f);
    float v = hbuf[(size_t)r * kDp + tid];
    float p = fmaxf((v - mu) * istd * gamma[tid] + beta[tid], 0.f);
    float ss = p * p;
#pragma unroll
    for (int o = 32; o >= 1; o >>= 1) ss += __shfl_xor(ss, o);
    __shared__ float wsum[4];
    if ((tid & 63) == 0) wsum[tid >> 6] = ss;
    __syncthreads();
    float tot = wsum[0] + wsum[1] + wsum[2] + wsum[3];
    float scale = 1.f / fmaxf(sqrtf(tot), 1e-12f);
    hbuf[(size_t)r * kDp + tid] = p * scale;
}

// ---------------------------------------------------------------------------
// Combined similarity GEMMs: Kp (64x64) and Ke (0.5, 192x192) per batch.
// ---------------------------------------------------------------------------
__global__ __launch_bounds__(256) void gemm_sim(const float* __restrict__ hbuf,
                                                float* __restrict__ Kp,
                                                float* __restrict__ Ke)
{
    const int id = blockIdx.x, b = blockIdx.y, t = threadIdx.x;
    int mt, nt, ldo; const float *X, *Y; float* outp; float scale;
    if (id < 4) {
        mt = (id >> 1) * 32; nt = (id & 1) * 32; ldo = 64;
        X = hbuf + (size_t)b * 64 * kDp;
        Y = hbuf + (512 + (size_t)b * 64) * kDp;
        outp = Kp + (size_t)b * 4096; scale = 1.0f;
    } else {
        int e = id - 4;
        mt = (e / 6) * 32; nt = (e % 6) * 32; ldo = 192;
        X = hbuf + (1024 + (size_t)b * 192) * kDp;
        Y = hbuf + (2560 + (size_t)b * 192) * kDp;
        outp = Ke + (size_t)b * 36864; scale = 0.5f;
    }
    __shared__ float Xs[32][36];
    __shared__ float Ys[32][36];
    const int row = t >> 3, kq = t & 7;
    const int ty = t >> 4, tx = t & 15;
    float acc[2][2] = {};
    for (int k0 = 0; k0 < kDp; k0 += 32) {
        float4 xa = *(const float4*)(X + (size_t)(mt + row) * kDp + k0 + kq * 4);
        float4 ya = *(const float4*)(Y + (size_t)(nt + row) * kDp + k0 + kq * 4);
        Xs[kq * 4 + 0][row] = xa.x; Xs[kq * 4 + 1][row] = xa.y;
        Xs[kq * 4 + 2][row] = xa.z; Xs[kq * 4 + 3][row] = xa.w;
        Ys[kq * 4 + 0][row] = ya.x; Ys[kq * 4 + 1][row] = ya.y;
        Ys[kq * 4 + 2][row] = ya.z; Ys[kq * 4 + 3][row] = ya.w;
        __syncthreads();
#pragma unroll
        for (int kk = 0; kk < 32; ++kk) {
            float2 xv = *(const float2*)&Xs[kk][ty * 2];
            float2 yv = *(const float2*)&Ys[kk][tx * 2];
            acc[0][0] += xv.x * yv.x; acc[0][1] += xv.x * yv.y;
            acc[1][0] += xv.y * yv.x; acc[1][1] += xv.y * yv.y;
        }
        __syncthreads();
    }
#pragma unroll
    for (int i = 0; i < 2; ++i)
#pragma unroll
        for (int j = 0; j < 2; ++j)
            outp[(size_t)(mt + ty * 2 + i) * ldo + nt + tx * 2 + j] = scale * acc[i][j];
}

// ---------------------------------------------------------------------------
// Per-batch: source-node CSR (for layer_k) + class reps via LDS atomicMin
// keymaps + class-CSR (counting sort by representative).
// ---------------------------------------------------------------------------
__global__ __launch_bounds__(256) void build_csr(
    const int* __restrict__ s1, const int* __restrict__ d1,
    const int* __restrict__ s2, const int* __restrict__ d2,
    int* __restrict__ off1, int* __restrict__ lst1,
    int* __restrict__ off2, int* __restrict__ lst2,
    int* __restrict__ rep1g, int* __restrict__ rep2g,
    int* __restrict__ coff1, int* __restrict__ clst1,
    int* __restrict__ coff2, int* __restrict__ clst2)
{
    int b = blockIdx.x, t = threadIdx.x;
    __shared__ int km1[4096], km2[4096];
    __shared__ short es1[kE], es2[kE];
    __shared__ short rp1[kE], rp2[kE];
    __shared__ int cnt1[64], cnt2[64], pos1[64], pos2[64];
    __shared__ int ccnt1[kE], ccnt2[kE], cpos1[kE], cpos2[kE];

    for (int i = t; i < 4096; i += 256) { km1[i] = 0x7fffffff; km2[i] = 0x7fffffff; }
    if (t < 64) { cnt1[t] = 0; cnt2[t] = 0; }
    for (int i = t; i < kE; i += 256) { ccnt1[i] = 0; ccnt2[i] = 0; }
    __syncthreads();

    if (t < kE) {
        int v1 = s1[b * kE + t], v2 = s2[b * kE + t];
        es1[t] = (short)v1; es2[t] = (short)v2;
        atomicAdd(&cnt1[v1], 1);
        atomicAdd(&cnt2[v2], 1);
        atomicMin(&km1[v1 * 64 + d1[b * kE + t]], t);
        atomicMin(&km2[v2 * 64 + d2[b * kE + t]], t);
    }
    __syncthreads();

    if (t < kE) {
        int r1 = km1[es1[t] * 64 + d1[b * kE + t]];
        int r2 = km2[es2[t] * 64 + d2[b * kE + t]];
        rp1[t] = (short)r1; rp2[t] = (short)r2;
        rep1g[b * kE + t] = r1; rep2g[b * kE + t] = r2;
        atomicAdd(&ccnt1[r1], 1);
        atomicAdd(&ccnt2[r2], 1);
    }
    __syncthreads();

    if (t == 0) {
        int a = 0, c = 0;
        for (int v = 0; v < 64; ++v) { pos1[v] = a; a += cnt1[v]; pos2[v] = c; c += cnt2[v]; }
        a = 0; c = 0;
        for (int v = 0; v < kE; ++v) { cpos1[v] = a; a += ccnt1[v]; cpos2[v] = c; c += ccnt2[v]; }
    }
    __syncthreads();

    if (t < 64) { off1[b * 65 + t] = pos1[t]; off2[b * 65 + t] = pos2[t]; }
    if (t == 0) { off1[b * 65 + 64] = kE; off2[b * 65 + 64] = kE; }
    if (t < kE) { coff1[b * 193 + t] = cpos1[t]; coff2[b * 193 + t] = cpos2[t]; }
    if (t == 0) { coff1[b * 193 + kE] = kE; coff2[b * 193 + kE] = kE; }
    __syncthreads();

    if (t < kE) {
        int p = atomicAdd(&pos1[es1[t]], 1); lst1[b * kE + p] = t;
        int q = atomicAdd(&pos2[es2[t]], 1); lst2[b * kE + q] = t;
        int cp = atomicAdd(&cpos1[rp1[t]], 1); clst1[b * kE + cp] = t;
        int cq = atomicAdd(&cpos2[rp2[t]], 1); clst2[b * kE + cq] = t;
    }
}

// ---------------------------------------------------------------------------
// Degree count: one thread per (i,j) pair; canonical pairs compute their
// accumulated class-pair sum directly (avg ~1 Ke load) and bump degcnt[r].
// ---------------------------------------------------------------------------
__global__ __launch_bounds__(256) void pairdeg(
    const int* __restrict__ s1, const int* __restrict__ d1,
    const int* __restrict__ s2, const int* __restrict__ d2,
    const int* __restrict__ rep1g, const int* __restrict__ rep2g,
    const int* __restrict__ coff1, const int* __restrict__ clst1,
    const int* __restrict__ coff2, const int* __restrict__ clst2,
    const float* __restrict__ Ke, int* __restrict__ degcnt)
{
    const int b = blockIdx.y, t = threadIdx.x;
    __shared__ short rs1[kE], rd1[kE], rs2[kE], rd2[kE];
    __shared__ short rp1[kE], rp2[kE];
    __shared__ int co1[kE + 1], co2[kE + 1];
    __shared__ short cl1[kE], cl2[kE];

    for (int i = t; i < kE; i += 256) {
        rs1[i] = (short)s1[b * kE + i]; rd1[i] = (short)d1[b * kE + i];
        rs2[i] = (short)s2[b * kE + i]; rd2[i] = (short)d2[b * kE + i];
        rp1[i] = (short)rep1g[b * kE + i]; rp2[i] = (short)rep2g[b * kE + i];
        cl1[i] = (short)clst1[b * kE + i]; cl2[i] = (short)clst2[b * kE + i];
    }
    for (int i = t; i < kE + 1; i += 256) {
        co1[i] = coff1[b * 193 + i]; co2[i] = coff2[b * 193 + i];
    }
    __syncthreads();

    int idx = blockIdx.x * 256 + t;
    if (idx >= kE * kE) return;
    int i = idx / kE, j = idx - i * kE;
    if (rp1[i] != i || rp2[j] != j) return;

    const float* Keb = Ke + (size_t)b * kE * kE;
    float sum = 0.f;
    for (int m = co1[i]; m < co1[i + 1]; ++m) {
        int ii = cl1[m];
        const float* kr = Keb + (size_t)ii * kE;
        for (int n = co2[j]; n < co2[j + 1]; ++n) sum += kr[cl2[n]];
    }
    int r = rs2[j] * 64 + rs1[i];
    int c = rd2[j] * 64 + rd1[i];
    if (r != c && sum > 0.0f) atomicAdd(&degcnt[b * kNN + r], 1);
}

__global__ __launch_bounds__(256) void deg_fin(const int* __restrict__ degcnt,
                                               const float* __restrict__ Kp,
                                               float* __restrict__ deg,
                                               float* __restrict__ kdiag)
{
    int idx = blockIdx.x * 256 + threadIdx.x;
    int b = idx >> 12, r = idx & 4095;
    float kd = Kp[b * kNN + (r & 63) * kN + (r >> 6)];
    int d = degcnt[idx] + (kd > 0.0f ? 1 : 0);
    deg[idx] = fmaxf((float)d, 1.0f);
    kdiag[idx] = kd;
}

// ---------------------------------------------------------------------------
// Fused message-gather + layer MLP (verified R3)
// ---------------------------------------------------------------------------
template <int C>
__global__ __launch_bounds__(256) void layer_k(
    const int* __restrict__ off1, const int* __restrict__ lst1,
    const int* __restrict__ off2, const int* __restrict__ lst2,
    const int* __restrict__ d1, const int* __restrict__ d2,
    const float* __restrict__ Ke, const float* __restrict__ x,
    const float* __restrict__ kdiag, const float* __restrict__ deg,
    const float* __restrict__ W, const float* __restrict__ bb,
    const float* __restrict__ S, const float* __restrict__ c0,
    float* __restrict__ xn, float* __restrict__ vbuf)
{
    const int r2 = blockIdx.x, b = blockIdx.y, t = threadIdx.x;
    __shared__ float WL[C * 16];
    __shared__ float bL[16], SL[16];
    __shared__ float c0v;
    __shared__ int jd2[kE];
    __shared__ int il[kE];
    __shared__ float msgT[64][18];

    for (int k = t; k < C * 16; k += 256) WL[k] = W[k];
    if (t < 16) { bL[t] = bb[t]; SL[t] = S[t]; }
    if (t == 0) c0v = c0[0];
    const int j0 = off2[b * 65 + r2];
    const int n2 = off2[b * 65 + r2 + 1] - j0;
    for (int k = t; k < n2; k += 256) {
        int j = lst2[b * kE + j0 + k];
        jd2[k] = (j << 8) | d2[b * kE + j];
    }
    for (int k = t; k < kE; k += 256) {
        int i = lst1[b * kE + k];
        il[k] = (i << 8) | d1[b * kE + i];
    }
    __syncthreads();

    const int r1 = t >> 2, lane = t & 3;
    const int i0 = off1[b * 65 + r1], i1 = off1[b * 65 + r1 + 1];
    const float* Keb = Ke + (size_t)b * kE * kE;
    const float* xb  = x + (size_t)b * kNN * C;

    if (C == 1) {
        float acc = 0.f;
        for (int k = 0; k < n2; ++k) {
            int pk = jd2[k], j = pk >> 8, dd2 = pk & 255;
            const float* xrow = xb + dd2 * 64;
            for (int m = i0 + lane; m < i1; m += 4) {
                int pi = il[m], i = pi >> 8, dd1 = pi & 255;
                if (dd2 == r2 && dd1 == r1) continue;
                acc += Keb[(size_t)i * kE + j] * xrow[dd1];
            }
        }
        acc += __shfl_xor(acc, 1);
        acc += __shfl_xor(acc, 2);
        if (lane == 0) msgT[r1][0] = acc;
    } else {
        constexpr int NCH = (C + 3) / 4;
        float acc[NCH];
#pragma unroll
        for (int cc = 0; cc < NCH; ++cc) acc[cc] = 0.f;
        for (int k = 0; k < n2; ++k) {
            int pk = jd2[k], j = pk >> 8, dd2 = pk & 255;
            const float* xrow = xb + (size_t)(dd2 * 64) * C;
            for (int m = i0; m < i1; ++m) {
                int pi = il[m], i = pi >> 8, dd1 = pi & 255;
                if (dd2 == r2 && dd1 == r1) continue;
                float kv = Keb[(size_t)i * kE + j];
                const float* xc = xrow + dd1 * C;
#pragma unroll
                for (int cc = 0; cc < NCH; ++cc) {
                    int c = lane + cc * 4;
                    if (c < C) acc[cc] += kv * xc[c];
                }
            }
        }
#pragma unroll
        for (int cc = 0; cc < NCH; ++cc) {
            int c = lane + cc * 4;
            if (c < C) msgT[r1][c] = acc[cc];
        }
    }
    __syncthreads();

    const int row = r2 * 64 + r1;
    const int idx = b * kNN + row;
    const float kd = kdiag[idx];
    const float dg = deg[idx];
    float m[C];
#pragma unroll
    for (int c = 0; c < C; ++c)
        m[c] = (msgT[r1][c] + kd * xb[(size_t)row * C + c]) / dg;
    float vpart = 0.f;
#pragma unroll
    for (int ff = 0; ff < 4; ++ff) {
        int f = lane * 4 + ff;
        float a = bL[f];
#pragma unroll
        for (int c = 0; c < C; ++c) a += m[c] * WL[c * 16 + f];
        float h = fmaxf(a, 0.f);
        xn[(size_t)idx * 17 + f] = h;
        vpart += h * SL[f];
    }
    vpart += __shfl_xor(vpart, 1);
    vpart += __shfl_xor(vpart, 2);
    if (lane == 0) vbuf[idx] = vpart + c0v;
}

// ---------------------------------------------------------------------------
// Sinkhorn, 8 lanes per row, register-cached values (verified R3)
// ---------------------------------------------------------------------------
template <int NR, int THREADS, bool FINAL>
__global__ __launch_bounds__(THREADS) void sinkhorn_k(
    const float* __restrict__ vin, float* __restrict__ outp,
    const float* __restrict__ binvp, const float* __restrict__ Wc,
    const float* __restrict__ bc)
{
    __shared__ float mat[NR][68];
    __shared__ float WcL[17];
    __shared__ float bcv, binvv;
    const int b = blockIdx.x, tid = threadIdx.x;

    if (FINAL) {
        if (tid < 17) WcL[tid] = Wc[tid];
        if (tid == 17) bcv = bc[0];
        if (tid == 18) binvv = binvp[0];
        __syncthreads();
    }
    for (int idx = tid; idx < NR * NR; idx += THREADS) {
        int q = idx / NR, p = idx - q * NR;
        float val;
        if (FINAL) {
            if (p < kN && q < kN) {
                const float* xr = vin + (size_t)(b * kNN + q * kN + p) * 17;
                float v = bcv;
#pragma unroll
                for (int c = 0; c < 17; ++c) v += xr[c] * WcL[c];
                val = v;
            } else val = binvv;
        } else {
            val = vin[b * kNN + q * kN + p] * kTauInv;
        }
        mat[p][q] = val;
    }
    __syncthreads();

    const int r = tid >> 3, s = tid & 7;
    const bool act = r < NR;
    const int cnt = act ? ((NR - s + 7) >> 3) : 0;
    float vals[(NR + 7) / 8];

    for (int it = 0; it < 10; ++it) {
        float mx = -1e30f;
        for (int k = 0; k < cnt; ++k) { vals[k] = mat[r][s + 8 * k]; mx = fmaxf(mx, vals[k]); }
        mx = fmaxf(mx, __shfl_xor(mx, 1));
        mx = fmaxf(mx, __shfl_xor(mx, 2));
        mx = fmaxf(mx, __shfl_xor(mx, 4));
        float sum = 0.f;
        for (int k = 0; k < cnt; ++k) sum += __expf(vals[k] - mx);
        sum += __shfl_xor(sum, 1);
        sum += __shfl_xor(sum, 2);
        sum += __shfl_xor(sum, 4);
        float lse = mx + __logf(sum);
        for (int k = 0; k < cnt; ++k) mat[r][s + 8 * k] = vals[k] - lse;
        __syncthreads();
        mx = -1e30f;
        for (int k = 0; k < cnt; ++k) { vals[k] = mat[s + 8 * k][r]; mx = fmaxf(mx, vals[k]); }
        mx = fmaxf(mx, __shfl_xor(mx, 1));
        mx = fmaxf(mx, __shfl_xor(mx, 2));
        mx = fmaxf(mx, __shfl_xor(mx, 4));
        sum = 0.f;
        for (int k = 0; k < cnt; ++k) sum += __expf(vals[k] - mx);
        sum += __shfl_xor(sum, 1);
        sum += __shfl_xor(sum, 2);
        sum += __shfl_xor(sum, 4);
        lse = mx + __logf(sum);
        for (int k = 0; k < cnt; ++k) mat[s + 8 * k][r] = vals[k] - lse;
        __syncthreads();
    }

    for (int idx = tid; idx < NR * NR; idx += THREADS) {
        int q = idx / NR, p = idx - q * NR;
        float e = __expf(mat[p][q]);
        if (FINAL) {
            if (p < kN && q < kN) outp[((size_t)b * kN + p) * kN + q] = e;
        } else {
            outp[(size_t)(b * kNN + q * kN + p) * 17 + 16] = e;
        }
    }
}

__global__ __launch_bounds__(256) void max_reduce(const float* __restrict__ outp,
                                                  unsigned* __restrict__ maxbuf)
{
    int idx = blockIdx.x * 256 + threadIdx.x;
    float v = outp[idx];
#pragma unroll
    for (int o = 32; o >= 1; o >>= 1) v = fmaxf(v, __shfl_xor(v, o));
    __shared__ float w[4];
    if ((threadIdx.x & 63) == 0) w[threadIdx.x >> 6] = v;
    __syncthreads();
    if (threadIdx.x == 0) {
        v = fmaxf(fmaxf(w[0], w[1]), fmaxf(w[2], w[3]));
        atomicMax(maxbuf, __float_as_uint(v));
    }
}

__global__ __launch_bounds__(256) void scale_out(float* __restrict__ outp,
                                                 const unsigned* __restrict__ maxbuf)
{
    int idx = blockIdx.x * 256 + threadIdx.x;
    outp[idx] = outp[idx] / __uint_as_float(maxbuf[0]);
}

// ---------------------------------------------------------------------------
extern "C" void kernel_launch(void* const* d_in, const int* in_sizes, int n_in,
                              void* d_out, int out_size, void* d_ws, size_t ws_size,
                              hipStream_t stream)
{
    (void)in_sizes; (void)n_in; (void)out_size; (void)ws_size;

    const float* x1    = (const float*)d_in[0];
    const float* x2    = (const float*)d_in[1];
    const float* e1    = (const float*)d_in[2];
    const float* e2    = (const float*)d_in[3];
    const float* Wp    = (const float*)d_in[4];
    const float* bp    = (const float*)d_in[5];
    const float* gamma = (const float*)d_in[6];
    const float* beta  = (const float*)d_in[7];
    const float* W0 = (const float*)d_in[8];
    const float* b0 = (const float*)d_in[9];
    const float* S0 = (const float*)d_in[10];
    const float* c0 = (const float*)d_in[11];
    const float* W1 = (const float*)d_in[12];
    const float* b1 = (const float*)d_in[13];
    const float* S1 = (const float*)d_in[14];
    const float* c1 = (const float*)d_in[15];
    const float* W2 = (const float*)d_in[16];
    const float* b2 = (const float*)d_in[17];
    const float* S2 = (const float*)d_in[18];
    const float* c2 = (const float*)d_in[19];
    const float* Wc = (const float*)d_in[20];
    const float* bc = (const float*)d_in[21];
    const float* binv = (const float*)d_in[22];
    const int* src1 = (const int*)d_in[23];
    const int* dst1 = (const int*)d_in[24];
    const int* src2 = (const int*)d_in[25];
    const int* dst2 = (const int*)d_in[26];

    float* out = (float*)d_out;
    float* wsf = (float*)d_ws;

    // workspace carve (floats). P (2x1M partials) overlays the chain below.
    float* hbuf  = wsf;                    // 1,048,576
    float* P     = hbuf + 1048576;         // 2,097,152 (transient)
    float* Kp    = P;                      // 32768
    float* Ke    = Kp + 32768;             // 294912
    float* kdiag = Ke + 294912;            // 32768
    float* deg   = kdiag + 32768;          // 32768
    float* vbuf  = deg + 32768;            // 32768
    float* xA    = vbuf + 32768;           // 557056
    float* xB    = xA + 557056;            // 557056
    float* stats = xB + 557056;            // 2048
    int*   degcnt = (int*)(stats + 2048);  // 32768
    unsigned* maxbuf = (unsigned*)(degcnt + 32768); // 1
    int*   off1 = (int*)(maxbuf + 1);      // 520
    int*   off2 = off1 + 520;              // 520
    int*   lst1 = off2 + 520;              // 1536
    int*   lst2 = lst1 + 1536;             // 1536
    int*   rep1g = lst2 + 1536;            // 1536
    int*   rep2g = rep1g + 1536;           // 1536
    int*   coff1 = rep2g + 1536;           // 1544
    int*   coff2 = coff1 + 1544;           // 1544
    int*   clst1 = coff2 + 1544;           // 1536
    int*   clst2 = clst1 + 1536;           // 1536

    // ---- projection GEMM (K-split) + reduce ----
    gemm_proj<<<dim3(4, 64, 2), 256, 0, stream>>>(x1, x2, e1, e2, Wp, P);
    reduce_bias<<<1024, 256, 0, stream>>>(P, bp, hbuf);

    // zero stats + degcnt + maxbuf (contiguous) — after P is dead
    hipMemsetAsync(stats, 0, (2048 + 32768 + 1) * sizeof(float), stream);

    // ---- batchnorm + relu + l2norm ----
    bn_stats<<<dim3(8, 4), 256, 0, stream>>>(hbuf, stats);
    bn_norm_l2<<<4096, 256, 0, stream>>>(hbuf, stats, gamma, beta);

    // ---- similarity GEMMs ----
    gemm_sim<<<dim3(40, 8), 256, 0, stream>>>(hbuf, Kp, Ke);

    // ---- sparse K structure ----
    build_csr<<<8, 256, 0, stream>>>(src1, dst1, src2, dst2,
                                     off1, lst1, off2, lst2,
                                     rep1g, rep2g, coff1, clst1, coff2, clst2);
    pairdeg<<<dim3(144, 8), 256, 0, stream>>>(src1, dst1, src2, dst2,
                                              rep1g, rep2g, coff1, clst1, coff2, clst2,
                                              Ke, degcnt);
    deg_fin<<<128, 256, 0, stream>>>(degcnt, Kp, deg, kdiag);

    // ---- GNN layers (fused gather+MLP) + sinkhorns ----
    layer_k<1><<<dim3(64, 8), 256, 0, stream>>>(off1, lst1, off2, lst2, dst1, dst2,
                                                Ke, kdiag, kdiag, deg, W0, b0, S0, c0, xA, vbuf);
    sinkhorn_k<64, 512, false><<<8, 512, 0, stream>>>(vbuf, xA, nullptr, nullptr, nullptr);

    layer_k<17><<<dim3(64, 8), 256, 0, stream>>>(off1, lst1, off2, lst2, dst1, dst2,
                                                 Ke, xA, kdiag, deg, W1, b1, S1, c1, xB, vbuf);
    sinkhorn_k<64, 512, false><<<8, 512, 0, stream>>>(vbuf, xB, nullptr, nullptr, nullptr);

    layer_k<17><<<dim3(64, 8), 256, 0, stream>>>(off1, lst1, off2, lst2, dst1, dst2,
                                                 Ke, xB, kdiag, deg, W2, b2, S2, c2, xA, vbuf);
    sinkhorn_k<64, 512, false><<<8, 512, 0, stream>>>(vbuf, xA, nullptr, nullptr, nullptr);

    // ---- final: fused projection + bin-augmented sinkhorn + normalize ----
    sinkhorn_k<65, 576, true><<<8, 576, 0, stream>>>(xA, out, binv, Wc, bc);
    max_reduce<<<128, 256, 0, stream>>>(out, maxbuf);
    scale_out<<<128, 256, 0, stream>>>(out, maxbuf);
}

// Round 5
// 393.829 us; speedup vs baseline: 2.9585x; 1.0216x over previous
//
#include <hip/hip_runtime.h>

constexpr int kB   = 8;
constexpr int kN   = 64;
constexpr int kE   = 192;
constexpr int kDin = 1024;
constexpr int kDp  = 256;
constexpr int kNN  = 4096;
constexpr float kTauInv = 20.0f;

// ---------------------------------------------------------------------------
// Projection GEMM, K-split (z=2) + double-buffered LDS, partial out (no bias).
// ---------------------------------------------------------------------------
__global__ __launch_bounds__(256) void gemm_proj(
    const float* __restrict__ x1, const float* __restrict__ x2,
    const float* __restrict__ e1, const float* __restrict__ e2,
    const float* __restrict__ Wp, float* __restrict__ P)
{
    const int rt = blockIdx.y, ct = blockIdx.x, z = blockIdx.z;
    const int tid = threadIdx.x;
    const int tx = tid & 15, ty = tid >> 4;
    const int grow0 = rt * 64, col0 = ct * 64;

    const float* src; int lrow0;
    if (rt < 8)       { src = x1; lrow0 = grow0; }
    else if (rt < 16) { src = x2; lrow0 = grow0 - 512; }
    else if (rt < 40) { src = e1; lrow0 = grow0 - 1024; }
    else              { src = e2; lrow0 = grow0 - 2560; }

    __shared__ float As[2][16][68];
    __shared__ float Ws[2][16][68];

    const int arow = tid >> 2, acol = (tid & 3) * 4;
    const int wrow = tid >> 4, wcol = (tid & 15) * 4;

    const float* Abase = src + (size_t)(lrow0 + arow) * kDin + z * 512 + acol;
    const float* Wbase = Wp + (size_t)(z * 512 + wrow) * kDp + col0 + wcol;

    float4 a4 = *(const float4*)Abase;
    float4 w4 = *(const float4*)Wbase;

    float acc[4][4] = {};

    for (int c = 0; c < 32; ++c) {
        const int cur = c & 1;
        As[cur][acol + 0][arow] = a4.x;
        As[cur][acol + 1][arow] = a4.y;
        As[cur][acol + 2][arow] = a4.z;
        As[cur][acol + 3][arow] = a4.w;
        *(float4*)&Ws[cur][wrow][wcol] = w4;
        __syncthreads();
        if (c < 31) {
            a4 = *(const float4*)(Abase + (c + 1) * 16);
            w4 = *(const float4*)(Wbase + (size_t)(c + 1) * 16 * kDp);
        }
#pragma unroll
        for (int kk = 0; kk < 16; ++kk) {
            float4 av = *(const float4*)&As[cur][kk][ty * 4];
            float4 wv = *(const float4*)&Ws[cur][kk][tx * 4];
            float a[4] = {av.x, av.y, av.z, av.w};
            float w[4] = {wv.x, wv.y, wv.z, wv.w};
#pragma unroll
            for (int i = 0; i < 4; ++i)
#pragma unroll
                for (int j = 0; j < 4; ++j)
                    acc[i][j] += a[i] * w[j];
        }
    }
    float* Pz = P + (size_t)z * 1048576;
#pragma unroll
    for (int i = 0; i < 4; ++i)
#pragma unroll
        for (int j = 0; j < 4; ++j)
            Pz[(size_t)(grow0 + ty * 4 + i) * kDp + col0 + tx * 4 + j] = acc[i][j];
}

__global__ __launch_bounds__(256) void reduce_bias(const float* __restrict__ P,
                                                   const float* __restrict__ bp,
                                                   float* __restrict__ hbuf)
{
    int idx = blockIdx.x * 256 + threadIdx.x;
    float4 p0 = ((const float4*)P)[idx];
    float4 p1 = ((const float4*)(P + 1048576))[idx];
    float4 bb = ((const float4*)bp)[idx & 63];
    float4 r;
    r.x = p0.x + p1.x + bb.x; r.y = p0.y + p1.y + bb.y;
    r.z = p0.z + p1.z + bb.z; r.w = p0.w + p1.w + bb.w;
    ((float4*)hbuf)[idx] = r;
}

// ---------------------------------------------------------------------------
// BatchNorm stats: 256 blocks x 16 rows, fully-unrolled independent loads.
// Segment boundaries (512/1024/2560) are multiples of 16 -> block is seg-pure.
// ---------------------------------------------------------------------------
__global__ __launch_bounds__(256) void bn_stats(const float* __restrict__ hbuf,
                                                float* __restrict__ stats)
{
    int tid = threadIdx.x;
    int r0 = blockIdx.x * 16;
    int seg = (r0 < 512) ? 0 : (r0 < 1024 ? 1 : (r0 < 2560 ? 2 : 3));
    float s = 0.f, s2 = 0.f;
#pragma unroll
    for (int rr = 0; rr < 16; ++rr) {
        float v = hbuf[(size_t)(r0 + rr) * kDp + tid];
        s += v; s2 += v * v;
    }
    atomicAdd(&stats[seg * 512 + tid], s);
    atomicAdd(&stats[seg * 512 + 256 + tid], s2);
}

__global__ __launch_bounds__(256) void bn_norm_l2(float* hbuf,
                                                  const float* __restrict__ stats,
                                                  const float* __restrict__ gamma,
                                                  const float* __restrict__ beta)
{
    int r = blockIdx.x, tid = threadIdx.x;
    int seg = (r < 512) ? 0 : (r < 1024 ? 1 : (r < 2560 ? 2 : 3));
    float n = (seg < 2) ? 512.f : 1536.f;
    float mu   = stats[seg * 512 + tid] / n;
    float var  = stats[seg * 512 + 256 + tid] / n - mu * mu;
    float istd = rsqrtf(var + 1e-5f);
    float v = hbuf[(size_t)r * kDp + tid];
    float p = fmaxf((v - mu) * istd * gamma[tid] + beta[tid], 0.f);
    float ss = p * p;
#pragma unroll
    for (int o = 32; o >= 1; o >>= 1) ss += __shfl_xor(ss, o);
    __shared__ float wsum[4];
    if ((tid & 63) == 0) wsum[tid >> 6] = ss;
    __syncthreads();
    float tot = wsum[0] + wsum[1] + wsum[2] + wsum[3];
    float scale = 1.f / fmaxf(sqrtf(tot), 1e-12f);
    hbuf[(size_t)r * kDp + tid] = p * scale;
}

// ---------------------------------------------------------------------------
// Combined similarity GEMMs: Kp (64x64) and Ke (0.5, 192x192) per batch.
// ---------------------------------------------------------------------------
__global__ __launch_bounds__(256) void gemm_sim(const float* __restrict__ hbuf,
                                                float* __restrict__ Kp,
                                                float* __restrict__ Ke)
{
    const int id = blockIdx.x, b = blockIdx.y, t = threadIdx.x;
    int mt, nt, ldo; const float *X, *Y; float* outp; float scale;
    if (id < 4) {
        mt = (id >> 1) * 32; nt = (id & 1) * 32; ldo = 64;
        X = hbuf + (size_t)b * 64 * kDp;
        Y = hbuf + (512 + (size_t)b * 64) * kDp;
        outp = Kp + (size_t)b * 4096; scale = 1.0f;
    } else {
        int e = id - 4;
        mt = (e / 6) * 32; nt = (e % 6) * 32; ldo = 192;
        X = hbuf + (1024 + (size_t)b * 192) * kDp;
        Y = hbuf + (2560 + (size_t)b * 192) * kDp;
        outp = Ke + (size_t)b * 36864; scale = 0.5f;
    }
    __shared__ float Xs[32][36];
    __shared__ float Ys[32][36];
    const int row = t >> 3, kq = t & 7;
    const int ty = t >> 4, tx = t & 15;
    float acc[2][2] = {};
    for (int k0 = 0; k0 < kDp; k0 += 32) {
        float4 xa = *(const float4*)(X + (size_t)(mt + row) * kDp + k0 + kq * 4);
        float4 ya = *(const float4*)(Y + (size_t)(nt + row) * kDp + k0 + kq * 4);
        Xs[kq * 4 + 0][row] = xa.x; Xs[kq * 4 + 1][row] = xa.y;
        Xs[kq * 4 + 2][row] = xa.z; Xs[kq * 4 + 3][row] = xa.w;
        Ys[kq * 4 + 0][row] = ya.x; Ys[kq * 4 + 1][row] = ya.y;
        Ys[kq * 4 + 2][row] = ya.z; Ys[kq * 4 + 3][row] = ya.w;
        __syncthreads();
#pragma unroll
        for (int kk = 0; kk < 32; ++kk) {
            float2 xv = *(const float2*)&Xs[kk][ty * 2];
            float2 yv = *(const float2*)&Ys[kk][tx * 2];
            acc[0][0] += xv.x * yv.x; acc[0][1] += xv.x * yv.y;
            acc[1][0] += xv.y * yv.x; acc[1][1] += xv.y * yv.y;
        }
        __syncthreads();
    }
#pragma unroll
    for (int i = 0; i < 2; ++i)
#pragma unroll
        for (int j = 0; j < 2; ++j)
            outp[(size_t)(mt + ty * 2 + i) * ldo + nt + tx * 2 + j] = scale * acc[i][j];
}

// ---------------------------------------------------------------------------
// Per-batch: source-node CSR + class reps via LDS atomicMin keymaps + class-CSR
// ---------------------------------------------------------------------------
__global__ __launch_bounds__(256) void build_csr(
    const int* __restrict__ s1, const int* __restrict__ d1,
    const int* __restrict__ s2, const int* __restrict__ d2,
    int* __restrict__ off1, int* __restrict__ lst1,
    int* __restrict__ off2, int* __restrict__ lst2,
    int* __restrict__ rep1g, int* __restrict__ rep2g,
    int* __restrict__ coff1, int* __restrict__ clst1,
    int* __restrict__ coff2, int* __restrict__ clst2)
{
    int b = blockIdx.x, t = threadIdx.x;
    __shared__ int km1[4096], km2[4096];
    __shared__ short es1[kE], es2[kE];
    __shared__ short rp1[kE], rp2[kE];
    __shared__ int cnt1[64], cnt2[64], pos1[64], pos2[64];
    __shared__ int ccnt1[kE], ccnt2[kE], cpos1[kE], cpos2[kE];

    for (int i = t; i < 4096; i += 256) { km1[i] = 0x7fffffff; km2[i] = 0x7fffffff; }
    if (t < 64) { cnt1[t] = 0; cnt2[t] = 0; }
    for (int i = t; i < kE; i += 256) { ccnt1[i] = 0; ccnt2[i] = 0; }
    __syncthreads();

    if (t < kE) {
        int v1 = s1[b * kE + t], v2 = s2[b * kE + t];
        es1[t] = (short)v1; es2[t] = (short)v2;
        atomicAdd(&cnt1[v1], 1);
        atomicAdd(&cnt2[v2], 1);
        atomicMin(&km1[v1 * 64 + d1[b * kE + t]], t);
        atomicMin(&km2[v2 * 64 + d2[b * kE + t]], t);
    }
    __syncthreads();

    if (t < kE) {
        int r1 = km1[es1[t] * 64 + d1[b * kE + t]];
        int r2 = km2[es2[t] * 64 + d2[b * kE + t]];
        rp1[t] = (short)r1; rp2[t] = (short)r2;
        rep1g[b * kE + t] = r1; rep2g[b * kE + t] = r2;
        atomicAdd(&ccnt1[r1], 1);
        atomicAdd(&ccnt2[r2], 1);
    }
    __syncthreads();

    if (t == 0) {
        int a = 0, c = 0;
        for (int v = 0; v < 64; ++v) { pos1[v] = a; a += cnt1[v]; pos2[v] = c; c += cnt2[v]; }
        a = 0; c = 0;
        for (int v = 0; v < kE; ++v) { cpos1[v] = a; a += ccnt1[v]; cpos2[v] = c; c += ccnt2[v]; }
    }
    __syncthreads();

    if (t < 64) { off1[b * 65 + t] = pos1[t]; off2[b * 65 + t] = pos2[t]; }
    if (t == 0) { off1[b * 65 + 64] = kE; off2[b * 65 + 64] = kE; }
    if (t < kE) { coff1[b * 193 + t] = cpos1[t]; coff2[b * 193 + t] = cpos2[t]; }
    if (t == 0) { coff1[b * 193 + kE] = kE; coff2[b * 193 + kE] = kE; }
    __syncthreads();

    if (t < kE) {
        int p = atomicAdd(&pos1[es1[t]], 1); lst1[b * kE + p] = t;
        int q = atomicAdd(&pos2[es2[t]], 1); lst2[b * kE + q] = t;
        int cp = atomicAdd(&cpos1[rp1[t]], 1); clst1[b * kE + cp] = t;
        int cq = atomicAdd(&cpos2[rp2[t]], 1); clst2[b * kE + cq] = t;
    }
}

// ---------------------------------------------------------------------------
// Degree count: one thread per (i,j) pair (verified R4)
// ---------------------------------------------------------------------------
__global__ __launch_bounds__(256) void pairdeg(
    const int* __restrict__ s1, const int* __restrict__ d1,
    const int* __restrict__ s2, const int* __restrict__ d2,
    const int* __restrict__ rep1g, const int* __restrict__ rep2g,
    const int* __restrict__ coff1, const int* __restrict__ clst1,
    const int* __restrict__ coff2, const int* __restrict__ clst2,
    const float* __restrict__ Ke, int* __restrict__ degcnt)
{
    const int b = blockIdx.y, t = threadIdx.x;
    __shared__ short rs1[kE], rd1[kE], rs2[kE], rd2[kE];
    __shared__ short rp1[kE], rp2[kE];
    __shared__ int co1[kE + 1], co2[kE + 1];
    __shared__ short cl1[kE], cl2[kE];

    for (int i = t; i < kE; i += 256) {
        rs1[i] = (short)s1[b * kE + i]; rd1[i] = (short)d1[b * kE + i];
        rs2[i] = (short)s2[b * kE + i]; rd2[i] = (short)d2[b * kE + i];
        rp1[i] = (short)rep1g[b * kE + i]; rp2[i] = (short)rep2g[b * kE + i];
        cl1[i] = (short)clst1[b * kE + i]; cl2[i] = (short)clst2[b * kE + i];
    }
    for (int i = t; i < kE + 1; i += 256) {
        co1[i] = coff1[b * 193 + i]; co2[i] = coff2[b * 193 + i];
    }
    __syncthreads();

    int idx = blockIdx.x * 256 + t;
    if (idx >= kE * kE) return;
    int i = idx / kE, j = idx - i * kE;
    if (rp1[i] != i || rp2[j] != j) return;

    const float* Keb = Ke + (size_t)b * kE * kE;
    float sum = 0.f;
    for (int m = co1[i]; m < co1[i + 1]; ++m) {
        int ii = cl1[m];
        const float* kr = Keb + (size_t)ii * kE;
        for (int n = co2[j]; n < co2[j + 1]; ++n) sum += kr[cl2[n]];
    }
    int r = rs2[j] * 64 + rs1[i];
    int c = rd2[j] * 64 + rd1[i];
    if (r != c && sum > 0.0f) atomicAdd(&degcnt[b * kNN + r], 1);
}

__global__ __launch_bounds__(256) void deg_fin(const int* __restrict__ degcnt,
                                               const float* __restrict__ Kp,
                                               float* __restrict__ deg,
                                               float* __restrict__ kdiag)
{
    int idx = blockIdx.x * 256 + threadIdx.x;
    int b = idx >> 12, r = idx & 4095;
    float kd = Kp[b * kNN + (r & 63) * kN + (r >> 6)];
    int d = degcnt[idx] + (kd > 0.0f ? 1 : 0);
    deg[idx] = fmaxf((float)d, 1.0f);
    kdiag[idx] = kd;
}

// ---------------------------------------------------------------------------
// Fused message-gather + layer MLP (verified R3/R4)
// ---------------------------------------------------------------------------
template <int C>
__global__ __launch_bounds__(256) void layer_k(
    const int* __restrict__ off1, const int* __restrict__ lst1,
    const int* __restrict__ off2, const int* __restrict__ lst2,
    const int* __restrict__ d1, const int* __restrict__ d2,
    const float* __restrict__ Ke, const float* __restrict__ x,
    const float* __restrict__ kdiag, const float* __restrict__ deg,
    const float* __restrict__ W, const float* __restrict__ bb,
    const float* __restrict__ S, const float* __restrict__ c0,
    float* __restrict__ xn, float* __restrict__ vbuf)
{
    const int r2 = blockIdx.x, b = blockIdx.y, t = threadIdx.x;
    __shared__ float WL[C * 16];
    __shared__ float bL[16], SL[16];
    __shared__ float c0v;
    __shared__ int jd2[kE];
    __shared__ int il[kE];
    __shared__ float msgT[64][18];

    for (int k = t; k < C * 16; k += 256) WL[k] = W[k];
    if (t < 16) { bL[t] = bb[t]; SL[t] = S[t]; }
    if (t == 0) c0v = c0[0];
    const int j0 = off2[b * 65 + r2];
    const int n2 = off2[b * 65 + r2 + 1] - j0;
    for (int k = t; k < n2; k += 256) {
        int j = lst2[b * kE + j0 + k];
        jd2[k] = (j << 8) | d2[b * kE + j];
    }
    for (int k = t; k < kE; k += 256) {
        int i = lst1[b * kE + k];
        il[k] = (i << 8) | d1[b * kE + i];
    }
    __syncthreads();

    const int r1 = t >> 2, lane = t & 3;
    const int i0 = off1[b * 65 + r1], i1 = off1[b * 65 + r1 + 1];
    const float* Keb = Ke + (size_t)b * kE * kE;
    const float* xb  = x + (size_t)b * kNN * C;

    if (C == 1) {
        float acc = 0.f;
        for (int k = 0; k < n2; ++k) {
            int pk = jd2[k], j = pk >> 8, dd2 = pk & 255;
            const float* xrow = xb + dd2 * 64;
            for (int m = i0 + lane; m < i1; m += 4) {
                int pi = il[m], i = pi >> 8, dd1 = pi & 255;
                if (dd2 == r2 && dd1 == r1) continue;
                acc += Keb[(size_t)i * kE + j] * xrow[dd1];
            }
        }
        acc += __shfl_xor(acc, 1);
        acc += __shfl_xor(acc, 2);
        if (lane == 0) msgT[r1][0] = acc;
    } else {
        constexpr int NCH = (C + 3) / 4;
        float acc[NCH];
#pragma unroll
        for (int cc = 0; cc < NCH; ++cc) acc[cc] = 0.f;
        for (int k = 0; k < n2; ++k) {
            int pk = jd2[k], j = pk >> 8, dd2 = pk & 255;
            const float* xrow = xb + (size_t)(dd2 * 64) * C;
            for (int m = i0; m < i1; ++m) {
                int pi = il[m], i = pi >> 8, dd1 = pi & 255;
                if (dd2 == r2 && dd1 == r1) continue;
                float kv = Keb[(size_t)i * kE + j];
                const float* xc = xrow + dd1 * C;
#pragma unroll
                for (int cc = 0; cc < NCH; ++cc) {
                    int c = lane + cc * 4;
                    if (c < C) acc[cc] += kv * xc[c];
                }
            }
        }
#pragma unroll
        for (int cc = 0; cc < NCH; ++cc) {
            int c = lane + cc * 4;
            if (c < C) msgT[r1][c] = acc[cc];
        }
    }
    __syncthreads();

    const int row = r2 * 64 + r1;
    const int idx = b * kNN + row;
    const float kd = kdiag[idx];
    const float dg = deg[idx];
    float m[C];
#pragma unroll
    for (int c = 0; c < C; ++c)
        m[c] = (msgT[r1][c] + kd * xb[(size_t)row * C + c]) / dg;
    float vpart = 0.f;
#pragma unroll
    for (int ff = 0; ff < 4; ++ff) {
        int f = lane * 4 + ff;
        float a = bL[f];
#pragma unroll
        for (int c = 0; c < C; ++c) a += m[c] * WL[c * 16 + f];
        float h = fmaxf(a, 0.f);
        xn[(size_t)idx * 17 + f] = h;
        vpart += h * SL[f];
    }
    vpart += __shfl_xor(vpart, 1);
    vpart += __shfl_xor(vpart, 2);
    if (lane == 0) vbuf[idx] = vpart + c0v;
}

// ---------------------------------------------------------------------------
// Sinkhorn via dual potentials: ls_k = L + f + g, f = -lse_q(L+g), g = -lse_p(L+f).
// L cached in registers (row slice + col slice); loop touches only f/g in LDS.
// Exactly equivalent to the reference log-domain recursion.
// ---------------------------------------------------------------------------
template <int NR, int THREADS, bool FINAL>
__global__ __launch_bounds__(THREADS) void sinkhorn_k(
    const float* __restrict__ vin, float* __restrict__ outp,
    const float* __restrict__ binvp, const float* __restrict__ Wc,
    const float* __restrict__ bc)
{
    constexpr int MAXK = (NR + 7) / 8;
    __shared__ float mat[NR][68];
    __shared__ float fL[NR], gL[NR];
    __shared__ float WcL[17];
    __shared__ float bcv, binvv;
    const int b = blockIdx.x, tid = threadIdx.x;

    if (FINAL) {
        if (tid < 17) WcL[tid] = Wc[tid];
        if (tid == 17) bcv = bc[0];
        if (tid == 18) binvv = binvp[0];
        __syncthreads();
    }
    for (int idx = tid; idx < NR * NR; idx += THREADS) {
        int q = idx / NR, p = idx - q * NR;
        float val;
        if (FINAL) {
            if (p < kN && q < kN) {
                const float* xr = vin + (size_t)(b * kNN + q * kN + p) * 17;
                float v = bcv;
#pragma unroll
                for (int c = 0; c < 17; ++c) v += xr[c] * WcL[c];
                val = v;
            } else val = binvv;
        } else {
            val = vin[b * kNN + q * kN + p] * kTauInv;
        }
        mat[p][q] = val;
    }
    if (tid < NR) { fL[tid] = 0.f; gL[tid] = 0.f; }
    __syncthreads();

    const int r = tid >> 3, s = tid & 7;
    const bool act = r < NR;
    const int cnt = act ? ((NR - s + 7) >> 3) : 0;
    float Lrow[MAXK], Lcol[MAXK];
    for (int k = 0; k < cnt; ++k) {
        Lrow[k] = mat[r][s + 8 * k];
        Lcol[k] = mat[s + 8 * k][r];
    }
    __syncthreads();

    float tv[MAXK];
    for (int it = 0; it < 10; ++it) {
        // f[p] = -lse_q(L[p][q] + g[q])
        float mx = -1e30f;
        for (int k = 0; k < cnt; ++k) { tv[k] = Lrow[k] + gL[s + 8 * k]; mx = fmaxf(mx, tv[k]); }
        mx = fmaxf(mx, __shfl_xor(mx, 1));
        mx = fmaxf(mx, __shfl_xor(mx, 2));
        mx = fmaxf(mx, __shfl_xor(mx, 4));
        float sum = 0.f;
        for (int k = 0; k < cnt; ++k) sum += __expf(tv[k] - mx);
        sum += __shfl_xor(sum, 1);
        sum += __shfl_xor(sum, 2);
        sum += __shfl_xor(sum, 4);
        if (act && s == 0) fL[r] = -(mx + __logf(sum));
        __syncthreads();
        // g[q] = -lse_p(L[p][q] + f[p])
        mx = -1e30f;
        for (int k = 0; k < cnt; ++k) { tv[k] = Lcol[k] + fL[s + 8 * k]; mx = fmaxf(mx, tv[k]); }
        mx = fmaxf(mx, __shfl_xor(mx, 1));
        mx = fmaxf(mx, __shfl_xor(mx, 2));
        mx = fmaxf(mx, __shfl_xor(mx, 4));
        sum = 0.f;
        for (int k = 0; k < cnt; ++k) sum += __expf(tv[k] - mx);
        sum += __shfl_xor(sum, 1);
        sum += __shfl_xor(sum, 2);
        sum += __shfl_xor(sum, 4);
        if (act && s == 0) gL[r] = -(mx + __logf(sum));
        __syncthreads();
    }

    // output: exp(L + f + g)
    if (act) {
        float fr = fL[r];
        for (int k = 0; k < cnt; ++k) {
            int q = s + 8 * k, p = r;
            float e = __expf(Lrow[k] + fr + gL[q]);
            if (FINAL) {
                if (p < kN && q < kN) outp[((size_t)b * kN + p) * kN + q] = e;
            } else {
                outp[(size_t)(b * kNN + q * kN + p) * 17 + 16] = e;
            }
        }
    }
}

__global__ __launch_bounds__(256) void max_reduce(const float* __restrict__ outp,
                                                  unsigned* __restrict__ maxbuf)
{
    int idx = blockIdx.x * 256 + threadIdx.x;
    float v = outp[idx];
#pragma unroll
    for (int o = 32; o >= 1; o >>= 1) v = fmaxf(v, __shfl_xor(v, o));
    __shared__ float w[4];
    if ((threadIdx.x & 63) == 0) w[threadIdx.x >> 6] = v;
    __syncthreads();
    if (threadIdx.x == 0) {
        v = fmaxf(fmaxf(w[0], w[1]), fmaxf(w[2], w[3]));
        atomicMax(maxbuf, __float_as_uint(v));
    }
}

__global__ __launch_bounds__(256) void scale_out(float* __restrict__ outp,
                                                 const unsigned* __restrict__ maxbuf)
{
    int idx = blockIdx.x * 256 + threadIdx.x;
    outp[idx] = outp[idx] / __uint_as_float(maxbuf[0]);
}

// ---------------------------------------------------------------------------
extern "C" void kernel_launch(void* const* d_in, const int* in_sizes, int n_in,
                              void* d_out, int out_size, void* d_ws, size_t ws_size,
                              hipStream_t stream)
{
    (void)in_sizes; (void)n_in; (void)out_size; (void)ws_size;

    const float* x1    = (const float*)d_in[0];
    const float* x2    = (const float*)d_in[1];
    const float* e1    = (const float*)d_in[2];
    const float* e2    = (const float*)d_in[3];
    const float* Wp    = (const float*)d_in[4];
    const float* bp    = (const float*)d_in[5];
    const float* gamma = (const float*)d_in[6];
    const float* beta  = (const float*)d_in[7];
    const float* W0 = (const float*)d_in[8];
    const float* b0 = (const float*)d_in[9];
    const float* S0 = (const float*)d_in[10];
    const float* c0 = (const float*)d_in[11];
    const float* W1 = (const float*)d_in[12];
    const float* b1 = (const float*)d_in[13];
    const float* S1 = (const float*)d_in[14];
    const float* c1 = (const float*)d_in[15];
    const float* W2 = (const float*)d_in[16];
    const float* b2 = (const float*)d_in[17];
    const float* S2 = (const float*)d_in[18];
    const float* c2 = (const float*)d_in[19];
    const float* Wc = (const float*)d_in[20];
    const float* bc = (const float*)d_in[21];
    const float* binv = (const float*)d_in[22];
    const int* src1 = (const int*)d_in[23];
    const int* dst1 = (const int*)d_in[24];
    const int* src2 = (const int*)d_in[25];
    const int* dst2 = (const int*)d_in[26];

    float* out = (float*)d_out;
    float* wsf = (float*)d_ws;

    // workspace carve (floats). P (2x1M partials) overlays the chain below.
    float* hbuf  = wsf;                    // 1,048,576
    float* P     = hbuf + 1048576;         // 2,097,152 (transient)
    float* Kp    = P;                      // 32768
    float* Ke    = Kp + 32768;             // 294912
    float* kdiag = Ke + 294912;            // 32768
    float* deg   = kdiag + 32768;          // 32768
    float* vbuf  = deg + 32768;            // 32768
    float* xA    = vbuf + 32768;           // 557056
    float* xB    = xA + 557056;            // 557056
    float* stats = xB + 557056;            // 2048
    int*   degcnt = (int*)(stats + 2048);  // 32768
    unsigned* maxbuf = (unsigned*)(degcnt + 32768); // 1
    int*   off1 = (int*)(maxbuf + 1);      // 520
    int*   off2 = off1 + 520;              // 520
    int*   lst1 = off2 + 520;              // 1536
    int*   lst2 = lst1 + 1536;             // 1536
    int*   rep1g = lst2 + 1536;            // 1536
    int*   rep2g = rep1g + 1536;           // 1536
    int*   coff1 = rep2g + 1536;           // 1544
    int*   coff2 = coff1 + 1544;           // 1544
    int*   clst1 = coff2 + 1544;           // 1536
    int*   clst2 = clst1 + 1536;           // 1536

    // ---- projection GEMM (K-split) + reduce ----
    gemm_proj<<<dim3(4, 64, 2), 256, 0, stream>>>(x1, x2, e1, e2, Wp, P);
    reduce_bias<<<1024, 256, 0, stream>>>(P, bp, hbuf);

    // zero stats + degcnt + maxbuf (contiguous) — after P is dead
    hipMemsetAsync(stats, 0, (2048 + 32768 + 1) * sizeof(float), stream);

    // ---- batchnorm + relu + l2norm ----
    bn_stats<<<256, 256, 0, stream>>>(hbuf, stats);
    bn_norm_l2<<<4096, 256, 0, stream>>>(hbuf, stats, gamma, beta);

    // ---- similarity GEMMs ----
    gemm_sim<<<dim3(40, 8), 256, 0, stream>>>(hbuf, Kp, Ke);

    // ---- sparse K structure ----
    build_csr<<<8, 256, 0, stream>>>(src1, dst1, src2, dst2,
                                     off1, lst1, off2, lst2,
                                     rep1g, rep2g, coff1, clst1, coff2, clst2);
    pairdeg<<<dim3(144, 8), 256, 0, stream>>>(src1, dst1, src2, dst2,
                                              rep1g, rep2g, coff1, clst1, coff2, clst2,
                                              Ke, degcnt);
    deg_fin<<<128, 256, 0, stream>>>(degcnt, Kp, deg, kdiag);

    // ---- GNN layers (fused gather+MLP) + sinkhorns ----
    layer_k<1><<<dim3(64, 8), 256, 0, stream>>>(off1, lst1, off2, lst2, dst1, dst2,
                                                Ke, kdiag, kdiag, deg, W0, b0, S0, c0, xA, vbuf);
    sinkhorn_k<64, 512, false><<<8, 512, 0, stream>>>(vbuf, xA, nullptr, nullptr, nullptr);

    layer_k<17><<<dim3(64, 8), 256, 0, stream>>>(off1, lst1, off2, lst2, dst1, dst2,
                                                 Ke, xA, kdiag, deg, W1, b1, S1, c1, xB, vbuf);
    sinkhorn_k<64, 512, false><<<8, 512, 0, stream>>>(vbuf, xB, nullptr, nullptr, nullptr);

    layer_k<17><<<dim3(64, 8), 256, 0, stream>>>(off1, lst1, off2, lst2, dst1, dst2,
                                                 Ke, xB, kdiag, deg, W2, b2, S2, c2, xA, vbuf);
    sinkhorn_k<64, 512, false><<<8, 512, 0, stream>>>(vbuf, xA, nullptr, nullptr, nullptr);

    // ---- final: fused projection + bin-augmented sinkhorn + normalize ----
    sinkhorn_k<65, 576, true><<<8, 576, 0, stream>>>(xA, out, binv, Wc, bc);
    max_reduce<<<128, 256, 0, stream>>>(out, maxbuf);
    scale_out<<<128, 256, 0, stream>>>(out, maxbuf);
}

// Round 6
// 387.560 us; speedup vs baseline: 3.0063x; 1.0162x over previous
//
#include <hip/hip_runtime.h>

constexpr int kB   = 8;
constexpr int kN   = 64;
constexpr int kE   = 192;
constexpr int kDin = 1024;
constexpr int kDp  = 256;
constexpr int kNN  = 4096;
constexpr float kTauInv = 20.0f;

// ---------------------------------------------------------------------------
// Projection GEMM, K-split (z=4) + double-buffered LDS, partial out (no bias).
// 64x64 tile, 256 threads, 4x4 micro-tile, K-chunk 16, one sync per chunk.
// ---------------------------------------------------------------------------
__global__ __launch_bounds__(256) void gemm_proj(
    const float* __restrict__ x1, const float* __restrict__ x2,
    const float* __restrict__ e1, const float* __restrict__ e2,
    const float* __restrict__ Wp, float* __restrict__ P)
{
    const int rt = blockIdx.y, ct = blockIdx.x, z = blockIdx.z;
    const int tid = threadIdx.x;
    const int tx = tid & 15, ty = tid >> 4;
    const int grow0 = rt * 64, col0 = ct * 64;

    const float* src; int lrow0;
    if (rt < 8)       { src = x1; lrow0 = grow0; }
    else if (rt < 16) { src = x2; lrow0 = grow0 - 512; }
    else if (rt < 40) { src = e1; lrow0 = grow0 - 1024; }
    else              { src = e2; lrow0 = grow0 - 2560; }

    __shared__ float As[2][16][68];
    __shared__ float Ws[2][16][68];

    const int arow = tid >> 2, acol = (tid & 3) * 4;
    const int wrow = tid >> 4, wcol = (tid & 15) * 4;

    const float* Abase = src + (size_t)(lrow0 + arow) * kDin + z * 256 + acol;
    const float* Wbase = Wp + (size_t)(z * 256 + wrow) * kDp + col0 + wcol;

    float4 a4 = *(const float4*)Abase;
    float4 w4 = *(const float4*)Wbase;

    float acc[4][4] = {};

    for (int c = 0; c < 16; ++c) {
        const int cur = c & 1;
        As[cur][acol + 0][arow] = a4.x;
        As[cur][acol + 1][arow] = a4.y;
        As[cur][acol + 2][arow] = a4.z;
        As[cur][acol + 3][arow] = a4.w;
        *(float4*)&Ws[cur][wrow][wcol] = w4;
        __syncthreads();
        if (c < 15) {
            a4 = *(const float4*)(Abase + (c + 1) * 16);
            w4 = *(const float4*)(Wbase + (size_t)(c + 1) * 16 * kDp);
        }
#pragma unroll
        for (int kk = 0; kk < 16; ++kk) {
            float4 av = *(const float4*)&As[cur][kk][ty * 4];
            float4 wv = *(const float4*)&Ws[cur][kk][tx * 4];
            float a[4] = {av.x, av.y, av.z, av.w};
            float w[4] = {wv.x, wv.y, wv.z, wv.w};
#pragma unroll
            for (int i = 0; i < 4; ++i)
#pragma unroll
                for (int j = 0; j < 4; ++j)
                    acc[i][j] += a[i] * w[j];
        }
    }
    float* Pz = P + (size_t)z * 1048576;
#pragma unroll
    for (int i = 0; i < 4; ++i)
#pragma unroll
        for (int j = 0; j < 4; ++j)
            Pz[(size_t)(grow0 + ty * 4 + i) * kDp + col0 + tx * 4 + j] = acc[i][j];
}

// hbuf = P0+P1+P2+P3 + bias; block 0 also zeroes stats (used by bn_stats later)
__global__ __launch_bounds__(256) void reduce_bias(const float* __restrict__ P,
                                                   const float* __restrict__ bp,
                                                   float* __restrict__ hbuf,
                                                   float* __restrict__ stats)
{
    int idx = blockIdx.x * 256 + threadIdx.x;
    if (blockIdx.x == 0) {
        for (int i = threadIdx.x; i < 2048; i += 256) stats[i] = 0.f;
    }
    float4 p0 = ((const float4*)P)[idx];
    float4 p1 = ((const float4*)(P + 1048576))[idx];
    float4 p2 = ((const float4*)(P + 2097152))[idx];
    float4 p3 = ((const float4*)(P + 3145728))[idx];
    float4 bb = ((const float4*)bp)[idx & 63];
    float4 r;
    r.x = p0.x + p1.x + p2.x + p3.x + bb.x;
    r.y = p0.y + p1.y + p2.y + p3.y + bb.y;
    r.z = p0.z + p1.z + p2.z + p3.z + bb.z;
    r.w = p0.w + p1.w + p2.w + p3.w + bb.w;
    ((float4*)hbuf)[idx] = r;
}

// ---------------------------------------------------------------------------
// BatchNorm stats: 256 blocks x 16 rows, fully-unrolled independent loads.
// ---------------------------------------------------------------------------
__global__ __launch_bounds__(256) void bn_stats(const float* __restrict__ hbuf,
                                                float* __restrict__ stats)
{
    int tid = threadIdx.x;
    int r0 = blockIdx.x * 16;
    int seg = (r0 < 512) ? 0 : (r0 < 1024 ? 1 : (r0 < 2560 ? 2 : 3));
    float s = 0.f, s2 = 0.f;
#pragma unroll
    for (int rr = 0; rr < 16; ++rr) {
        float v = hbuf[(size_t)(r0 + rr) * kDp + tid];
        s += v; s2 += v * v;
    }
    atomicAdd(&stats[seg * 512 + tid], s);
    atomicAdd(&stats[seg * 512 + 256 + tid], s2);
}

__global__ __launch_bounds__(256) void bn_norm_l2(float* hbuf,
                                                  const float* __restrict__ stats,
                                                  const float* __restrict__ gamma,
                                                  const float* __restrict__ beta)
{
    int r = blockIdx.x, tid = threadIdx.x;
    int seg = (r < 512) ? 0 : (r < 1024 ? 1 : (r < 2560 ? 2 : 3));
    float n = (seg < 2) ? 512.f : 1536.f;
    float mu   = stats[seg * 512 + tid] / n;
    float var  = stats[seg * 512 + 256 + tid] / n - mu * mu;
    float istd = rsqrtf(var + 1e-5f);
    float v = hbuf[(size_t)r * kDp + tid];
    float p = fmaxf((v - mu) * istd * gamma[tid] + beta[tid], 0.f);
    float ss = p * p;
#pragma unroll
    for (int o = 32; o >= 1; o >>= 1) ss += __shfl_xor(ss, o);
    __shared__ float wsum[4];
    if ((tid & 63) == 0) wsum[tid >> 6] = ss;
    __syncthreads();
    float tot = wsum[0] + wsum[1] + wsum[2] + wsum[3];
    float scale = 1.f / fmaxf(sqrtf(tot), 1e-12f);
    hbuf[(size_t)r * kDp + tid] = p * scale;
}

// ---------------------------------------------------------------------------
// Combined similarity GEMMs: Kp (64x64) and Ke (0.5, 192x192) per batch.
// ---------------------------------------------------------------------------
__global__ __launch_bounds__(256) void gemm_sim(const float* __restrict__ hbuf,
                                                float* __restrict__ Kp,
                                                float* __restrict__ Ke)
{
    const int id = blockIdx.x, b = blockIdx.y, t = threadIdx.x;
    int mt, nt, ldo; const float *X, *Y; float* outp; float scale;
    if (id < 4) {
        mt = (id >> 1) * 32; nt = (id & 1) * 32; ldo = 64;
        X = hbuf + (size_t)b * 64 * kDp;
        Y = hbuf + (512 + (size_t)b * 64) * kDp;
        outp = Kp + (size_t)b * 4096; scale = 1.0f;
    } else {
        int e = id - 4;
        mt = (e / 6) * 32; nt = (e % 6) * 32; ldo = 192;
        X = hbuf + (1024 + (size_t)b * 192) * kDp;
        Y = hbuf + (2560 + (size_t)b * 192) * kDp;
        outp = Ke + (size_t)b * 36864; scale = 0.5f;
    }
    __shared__ float Xs[32][36];
    __shared__ float Ys[32][36];
    const int row = t >> 3, kq = t & 7;
    const int ty = t >> 4, tx = t & 15;
    float acc[2][2] = {};
    for (int k0 = 0; k0 < kDp; k0 += 32) {
        float4 xa = *(const float4*)(X + (size_t)(mt + row) * kDp + k0 + kq * 4);
        float4 ya = *(const float4*)(Y + (size_t)(nt + row) * kDp + k0 + kq * 4);
        Xs[kq * 4 + 0][row] = xa.x; Xs[kq * 4 + 1][row] = xa.y;
        Xs[kq * 4 + 2][row] = xa.z; Xs[kq * 4 + 3][row] = xa.w;
        Ys[kq * 4 + 0][row] = ya.x; Ys[kq * 4 + 1][row] = ya.y;
        Ys[kq * 4 + 2][row] = ya.z; Ys[kq * 4 + 3][row] = ya.w;
        __syncthreads();
#pragma unroll
        for (int kk = 0; kk < 32; ++kk) {
            float2 xv = *(const float2*)&Xs[kk][ty * 2];
            float2 yv = *(const float2*)&Ys[kk][tx * 2];
            acc[0][0] += xv.x * yv.x; acc[0][1] += xv.x * yv.y;
            acc[1][0] += xv.y * yv.x; acc[1][1] += xv.y * yv.y;
        }
        __syncthreads();
    }
#pragma unroll
    for (int i = 0; i < 2; ++i)
#pragma unroll
        for (int j = 0; j < 2; ++j)
            outp[(size_t)(mt + ty * 2 + i) * ldo + nt + tx * 2 + j] = scale * acc[i][j];
}

// ---------------------------------------------------------------------------
// Per-batch: source-node CSR + class reps via LDS atomicMin keymaps + class-CSR.
// Also zeroes this batch's degcnt slice (consumed later by pairdeg).
// ---------------------------------------------------------------------------
__global__ __launch_bounds__(256) void build_csr(
    const int* __restrict__ s1, const int* __restrict__ d1,
    const int* __restrict__ s2, const int* __restrict__ d2,
    int* __restrict__ off1, int* __restrict__ lst1,
    int* __restrict__ off2, int* __restrict__ lst2,
    int* __restrict__ rep1g, int* __restrict__ rep2g,
    int* __restrict__ coff1, int* __restrict__ clst1,
    int* __restrict__ coff2, int* __restrict__ clst2,
    int* __restrict__ degcnt)
{
    int b = blockIdx.x, t = threadIdx.x;
    __shared__ int km1[4096], km2[4096];
    __shared__ short es1[kE], es2[kE];
    __shared__ short rp1[kE], rp2[kE];
    __shared__ int cnt1[64], cnt2[64], pos1[64], pos2[64];
    __shared__ int ccnt1[kE], ccnt2[kE], cpos1[kE], cpos2[kE];

    for (int i = t; i < 4096; i += 256) {
        km1[i] = 0x7fffffff; km2[i] = 0x7fffffff;
        degcnt[b * kNN + i] = 0;
    }
    if (t < 64) { cnt1[t] = 0; cnt2[t] = 0; }
    for (int i = t; i < kE; i += 256) { ccnt1[i] = 0; ccnt2[i] = 0; }
    __syncthreads();

    if (t < kE) {
        int v1 = s1[b * kE + t], v2 = s2[b * kE + t];
        es1[t] = (short)v1; es2[t] = (short)v2;
        atomicAdd(&cnt1[v1], 1);
        atomicAdd(&cnt2[v2], 1);
        atomicMin(&km1[v1 * 64 + d1[b * kE + t]], t);
        atomicMin(&km2[v2 * 64 + d2[b * kE + t]], t);
    }
    __syncthreads();

    if (t < kE) {
        int r1 = km1[es1[t] * 64 + d1[b * kE + t]];
        int r2 = km2[es2[t] * 64 + d2[b * kE + t]];
        rp1[t] = (short)r1; rp2[t] = (short)r2;
        rep1g[b * kE + t] = r1; rep2g[b * kE + t] = r2;
        atomicAdd(&ccnt1[r1], 1);
        atomicAdd(&ccnt2[r2], 1);
    }
    __syncthreads();

    if (t == 0) {
        int a = 0, c = 0;
        for (int v = 0; v < 64; ++v) { pos1[v] = a; a += cnt1[v]; pos2[v] = c; c += cnt2[v]; }
        a = 0; c = 0;
        for (int v = 0; v < kE; ++v) { cpos1[v] = a; a += ccnt1[v]; cpos2[v] = c; c += ccnt2[v]; }
    }
    __syncthreads();

    if (t < 64) { off1[b * 65 + t] = pos1[t]; off2[b * 65 + t] = pos2[t]; }
    if (t == 0) { off1[b * 65 + 64] = kE; off2[b * 65 + 64] = kE; }
    if (t < kE) { coff1[b * 193 + t] = cpos1[t]; coff2[b * 193 + t] = cpos2[t]; }
    if (t == 0) { coff1[b * 193 + kE] = kE; coff2[b * 193 + kE] = kE; }
    __syncthreads();

    if (t < kE) {
        int p = atomicAdd(&pos1[es1[t]], 1); lst1[b * kE + p] = t;
        int q = atomicAdd(&pos2[es2[t]], 1); lst2[b * kE + q] = t;
        int cp = atomicAdd(&cpos1[rp1[t]], 1); clst1[b * kE + cp] = t;
        int cq = atomicAdd(&cpos2[rp2[t]], 1); clst2[b * kE + cq] = t;
    }
}

// ---------------------------------------------------------------------------
// Degree count: one thread per (i,j) pair (verified R4/R5)
// ---------------------------------------------------------------------------
__global__ __launch_bounds__(256) void pairdeg(
    const int* __restrict__ s1, const int* __restrict__ d1,
    const int* __restrict__ s2, const int* __restrict__ d2,
    const int* __restrict__ rep1g, const int* __restrict__ rep2g,
    const int* __restrict__ coff1, const int* __restrict__ clst1,
    const int* __restrict__ coff2, const int* __restrict__ clst2,
    const float* __restrict__ Ke, int* __restrict__ degcnt)
{
    const int b = blockIdx.y, t = threadIdx.x;
    __shared__ short rs1[kE], rd1[kE], rs2[kE], rd2[kE];
    __shared__ short rp1[kE], rp2[kE];
    __shared__ int co1[kE + 1], co2[kE + 1];
    __shared__ short cl1[kE], cl2[kE];

    for (int i = t; i < kE; i += 256) {
        rs1[i] = (short)s1[b * kE + i]; rd1[i] = (short)d1[b * kE + i];
        rs2[i] = (short)s2[b * kE + i]; rd2[i] = (short)d2[b * kE + i];
        rp1[i] = (short)rep1g[b * kE + i]; rp2[i] = (short)rep2g[b * kE + i];
        cl1[i] = (short)clst1[b * kE + i]; cl2[i] = (short)clst2[b * kE + i];
    }
    for (int i = t; i < kE + 1; i += 256) {
        co1[i] = coff1[b * 193 + i]; co2[i] = coff2[b * 193 + i];
    }
    __syncthreads();

    int idx = blockIdx.x * 256 + t;
    if (idx >= kE * kE) return;
    int i = idx / kE, j = idx - i * kE;
    if (rp1[i] != i || rp2[j] != j) return;

    const float* Keb = Ke + (size_t)b * kE * kE;
    float sum = 0.f;
    for (int m = co1[i]; m < co1[i + 1]; ++m) {
        int ii = cl1[m];
        const float* kr = Keb + (size_t)ii * kE;
        for (int n = co2[j]; n < co2[j + 1]; ++n) sum += kr[cl2[n]];
    }
    int r = rs2[j] * 64 + rs1[i];
    int c = rd2[j] * 64 + rd1[i];
    if (r != c && sum > 0.0f) atomicAdd(&degcnt[b * kNN + r], 1);
}

__global__ __launch_bounds__(256) void deg_fin(const int* __restrict__ degcnt,
                                               const float* __restrict__ Kp,
                                               float* __restrict__ deg,
                                               float* __restrict__ kdiag)
{
    int idx = blockIdx.x * 256 + threadIdx.x;
    int b = idx >> 12, r = idx & 4095;
    float kd = Kp[b * kNN + (r & 63) * kN + (r >> 6)];
    int d = degcnt[idx] + (kd > 0.0f ? 1 : 0);
    deg[idx] = fmaxf((float)d, 1.0f);
    kdiag[idx] = kd;
}

// ---------------------------------------------------------------------------
// Fused message-gather + layer MLP (verified R3-R5)
// ---------------------------------------------------------------------------
template <int C>
__global__ __launch_bounds__(256) void layer_k(
    const int* __restrict__ off1, const int* __restrict__ lst1,
    const int* __restrict__ off2, const int* __restrict__ lst2,
    const int* __restrict__ d1, const int* __restrict__ d2,
    const float* __restrict__ Ke, const float* __restrict__ x,
    const float* __restrict__ kdiag, const float* __restrict__ deg,
    const float* __restrict__ W, const float* __restrict__ bb,
    const float* __restrict__ S, const float* __restrict__ c0,
    float* __restrict__ xn, float* __restrict__ vbuf)
{
    const int r2 = blockIdx.x, b = blockIdx.y, t = threadIdx.x;
    __shared__ float WL[C * 16];
    __shared__ float bL[16], SL[16];
    __shared__ float c0v;
    __shared__ int jd2[kE];
    __shared__ int il[kE];
    __shared__ float msgT[64][18];

    for (int k = t; k < C * 16; k += 256) WL[k] = W[k];
    if (t < 16) { bL[t] = bb[t]; SL[t] = S[t]; }
    if (t == 0) c0v = c0[0];
    const int j0 = off2[b * 65 + r2];
    const int n2 = off2[b * 65 + r2 + 1] - j0;
    for (int k = t; k < n2; k += 256) {
        int j = lst2[b * kE + j0 + k];
        jd2[k] = (j << 8) | d2[b * kE + j];
    }
    for (int k = t; k < kE; k += 256) {
        int i = lst1[b * kE + k];
        il[k] = (i << 8) | d1[b * kE + i];
    }
    __syncthreads();

    const int r1 = t >> 2, lane = t & 3;
    const int i0 = off1[b * 65 + r1], i1 = off1[b * 65 + r1 + 1];
    const float* Keb = Ke + (size_t)b * kE * kE;
    const float* xb  = x + (size_t)b * kNN * C;

    if (C == 1) {
        float acc = 0.f;
        for (int k = 0; k < n2; ++k) {
            int pk = jd2[k], j = pk >> 8, dd2 = pk & 255;
            const float* xrow = xb + dd2 * 64;
            for (int m = i0 + lane; m < i1; m += 4) {
                int pi = il[m], i = pi >> 8, dd1 = pi & 255;
                if (dd2 == r2 && dd1 == r1) continue;
                acc += Keb[(size_t)i * kE + j] * xrow[dd1];
            }
        }
        acc += __shfl_xor(acc, 1);
        acc += __shfl_xor(acc, 2);
        if (lane == 0) msgT[r1][0] = acc;
    } else {
        constexpr int NCH = (C + 3) / 4;
        float acc[NCH];
#pragma unroll
        for (int cc = 0; cc < NCH; ++cc) acc[cc] = 0.f;
        for (int k = 0; k < n2; ++k) {
            int pk = jd2[k], j = pk >> 8, dd2 = pk & 255;
            const float* xrow = xb + (size_t)(dd2 * 64) * C;
            for (int m = i0; m < i1; ++m) {
                int pi = il[m], i = pi >> 8, dd1 = pi & 255;
                if (dd2 == r2 && dd1 == r1) continue;
                float kv = Keb[(size_t)i * kE + j];
                const float* xc = xrow + dd1 * C;
#pragma unroll
                for (int cc = 0; cc < NCH; ++cc) {
                    int c = lane + cc * 4;
                    if (c < C) acc[cc] += kv * xc[c];
                }
            }
        }
#pragma unroll
        for (int cc = 0; cc < NCH; ++cc) {
            int c = lane + cc * 4;
            if (c < C) msgT[r1][c] = acc[cc];
        }
    }
    __syncthreads();

    const int row = r2 * 64 + r1;
    const int idx = b * kNN + row;
    const float kd = kdiag[idx];
    const float dg = deg[idx];
    float m[C];
#pragma unroll
    for (int c = 0; c < C; ++c)
        m[c] = (msgT[r1][c] + kd * xb[(size_t)row * C + c]) / dg;
    float vpart = 0.f;
#pragma unroll
    for (int ff = 0; ff < 4; ++ff) {
        int f = lane * 4 + ff;
        float a = bL[f];
#pragma unroll
        for (int c = 0; c < C; ++c) a += m[c] * WL[c * 16 + f];
        float h = fmaxf(a, 0.f);
        xn[(size_t)idx * 17 + f] = h;
        vpart += h * SL[f];
    }
    vpart += __shfl_xor(vpart, 1);
    vpart += __shfl_xor(vpart, 2);
    if (lane == 0) vbuf[idx] = vpart + c0v;
}

// ---------------------------------------------------------------------------
// Sinkhorn via dual potentials (verified R5)
// ---------------------------------------------------------------------------
template <int NR, int THREADS, bool FINAL>
__global__ __launch_bounds__(THREADS) void sinkhorn_k(
    const float* __restrict__ vin, float* __restrict__ outp,
    const float* __restrict__ binvp, const float* __restrict__ Wc,
    const float* __restrict__ bc)
{
    constexpr int MAXK = (NR + 7) / 8;
    __shared__ float mat[NR][68];
    __shared__ float fL[NR], gL[NR];
    __shared__ float WcL[17];
    __shared__ float bcv, binvv;
    const int b = blockIdx.x, tid = threadIdx.x;

    if (FINAL) {
        if (tid < 17) WcL[tid] = Wc[tid];
        if (tid == 17) bcv = bc[0];
        if (tid == 18) binvv = binvp[0];
        __syncthreads();
    }
    for (int idx = tid; idx < NR * NR; idx += THREADS) {
        int q = idx / NR, p = idx - q * NR;
        float val;
        if (FINAL) {
            if (p < kN && q < kN) {
                const float* xr = vin + (size_t)(b * kNN + q * kN + p) * 17;
                float v = bcv;
#pragma unroll
                for (int c = 0; c < 17; ++c) v += xr[c] * WcL[c];
                val = v;
            } else val = binvv;
        } else {
            val = vin[b * kNN + q * kN + p] * kTauInv;
        }
        mat[p][q] = val;
    }
    if (tid < NR) { fL[tid] = 0.f; gL[tid] = 0.f; }
    __syncthreads();

    const int r = tid >> 3, s = tid & 7;
    const bool act = r < NR;
    const int cnt = act ? ((NR - s + 7) >> 3) : 0;
    float Lrow[MAXK], Lcol[MAXK];
    for (int k = 0; k < cnt; ++k) {
        Lrow[k] = mat[r][s + 8 * k];
        Lcol[k] = mat[s + 8 * k][r];
    }
    __syncthreads();

    float tv[MAXK];
    for (int it = 0; it < 10; ++it) {
        float mx = -1e30f;
        for (int k = 0; k < cnt; ++k) { tv[k] = Lrow[k] + gL[s + 8 * k]; mx = fmaxf(mx, tv[k]); }
        mx = fmaxf(mx, __shfl_xor(mx, 1));
        mx = fmaxf(mx, __shfl_xor(mx, 2));
        mx = fmaxf(mx, __shfl_xor(mx, 4));
        float sum = 0.f;
        for (int k = 0; k < cnt; ++k) sum += __expf(tv[k] - mx);
        sum += __shfl_xor(sum, 1);
        sum += __shfl_xor(sum, 2);
        sum += __shfl_xor(sum, 4);
        if (act && s == 0) fL[r] = -(mx + __logf(sum));
        __syncthreads();
        mx = -1e30f;
        for (int k = 0; k < cnt; ++k) { tv[k] = Lcol[k] + fL[s + 8 * k]; mx = fmaxf(mx, tv[k]); }
        mx = fmaxf(mx, __shfl_xor(mx, 1));
        mx = fmaxf(mx, __shfl_xor(mx, 2));
        mx = fmaxf(mx, __shfl_xor(mx, 4));
        sum = 0.f;
        for (int k = 0; k < cnt; ++k) sum += __expf(tv[k] - mx);
        sum += __shfl_xor(sum, 1);
        sum += __shfl_xor(sum, 2);
        sum += __shfl_xor(sum, 4);
        if (act && s == 0) gL[r] = -(mx + __logf(sum));
        __syncthreads();
    }

    if (act) {
        float fr = fL[r];
        for (int k = 0; k < cnt; ++k) {
            int q = s + 8 * k, p = r;
            float e = __expf(Lrow[k] + fr + gL[q]);
            if (FINAL) {
                if (p < kN && q < kN) outp[((size_t)b * kN + p) * kN + q] = e;
            } else {
                outp[(size_t)(b * kNN + q * kN + p) * 17 + 16] = e;
            }
        }
    }
}

// ---------------------------------------------------------------------------
// Single-block global max + normalize (replaces max_reduce + scale_out).
// 1024 threads x 32 values held in registers.
// ---------------------------------------------------------------------------
__global__ __launch_bounds__(1024) void norm_out(float* __restrict__ outp)
{
    const int t = threadIdx.x;
    float4 v[8];
    float mx = -1e30f;
#pragma unroll
    for (int i = 0; i < 8; ++i) {
        v[i] = ((const float4*)outp)[t + i * 1024];
        mx = fmaxf(mx, fmaxf(fmaxf(v[i].x, v[i].y), fmaxf(v[i].z, v[i].w)));
    }
#pragma unroll
    for (int o = 32; o >= 1; o >>= 1) mx = fmaxf(mx, __shfl_xor(mx, o));
    __shared__ float wmax[16];
    if ((t & 63) == 0) wmax[t >> 6] = mx;
    __syncthreads();
    if (t < 16) {
        float m2 = wmax[t];
#pragma unroll
        for (int o = 8; o >= 1; o >>= 1) m2 = fmaxf(m2, __shfl_xor(m2, o));
        if (t == 0) wmax[0] = m2;
    }
    __syncthreads();
    float inv = 1.0f / wmax[0];
#pragma unroll
    for (int i = 0; i < 8; ++i) {
        float4 r;
        r.x = v[i].x * inv; r.y = v[i].y * inv;
        r.z = v[i].z * inv; r.w = v[i].w * inv;
        ((float4*)outp)[t + i * 1024] = r;
    }
}

// ---------------------------------------------------------------------------
extern "C" void kernel_launch(void* const* d_in, const int* in_sizes, int n_in,
                              void* d_out, int out_size, void* d_ws, size_t ws_size,
                              hipStream_t stream)
{
    (void)in_sizes; (void)n_in; (void)out_size; (void)ws_size;

    const float* x1    = (const float*)d_in[0];
    const float* x2    = (const float*)d_in[1];
    const float* e1    = (const float*)d_in[2];
    const float* e2    = (const float*)d_in[3];
    const float* Wp    = (const float*)d_in[4];
    const float* bp    = (const float*)d_in[5];
    const float* gamma = (const float*)d_in[6];
    const float* beta  = (const float*)d_in[7];
    const float* W0 = (const float*)d_in[8];
    const float* b0 = (const float*)d_in[9];
    const float* S0 = (const float*)d_in[10];
    const float* c0 = (const float*)d_in[11];
    const float* W1 = (const float*)d_in[12];
    const float* b1 = (const float*)d_in[13];
    const float* S1 = (const float*)d_in[14];
    const float* c1 = (const float*)d_in[15];
    const float* W2 = (const float*)d_in[16];
    const float* b2 = (const float*)d_in[17];
    const float* S2 = (const float*)d_in[18];
    const float* c2 = (const float*)d_in[19];
    const float* Wc = (const float*)d_in[20];
    const float* bc = (const float*)d_in[21];
    const float* binv = (const float*)d_in[22];
    const int* src1 = (const int*)d_in[23];
    const int* dst1 = (const int*)d_in[24];
    const int* src2 = (const int*)d_in[25];
    const int* dst2 = (const int*)d_in[26];

    float* out = (float*)d_out;
    float* wsf = (float*)d_ws;

    // workspace carve (floats) — non-overlapping, ~27 MB total
    float* hbuf  = wsf;                    // 1,048,576
    float* P     = hbuf + 1048576;         // 4,194,304
    float* Kp    = P + 4194304;            // 32768
    float* Ke    = Kp + 32768;             // 294912
    float* kdiag = Ke + 294912;            // 32768
    float* deg   = kdiag + 32768;          // 32768
    float* vbuf  = deg + 32768;            // 32768
    float* xA    = vbuf + 32768;           // 557056
    float* xB    = xA + 557056;            // 557056
    float* stats = xB + 557056;            // 2048
    int*   degcnt = (int*)(stats + 2048);  // 32768
    int*   off1 = degcnt + 32768;          // 520
    int*   off2 = off1 + 520;              // 520
    int*   lst1 = off2 + 520;              // 1536
    int*   lst2 = lst1 + 1536;             // 1536
    int*   rep1g = lst2 + 1536;            // 1536
    int*   rep2g = rep1g + 1536;           // 1536
    int*   coff1 = rep2g + 1536;           // 1544
    int*   coff2 = coff1 + 1544;           // 1544
    int*   clst1 = coff2 + 1544;           // 1536
    int*   clst2 = clst1 + 1536;           // 1536

    // ---- projection GEMM (K-split z=4) + reduce (also zeroes stats) ----
    gemm_proj<<<dim3(4, 64, 4), 256, 0, stream>>>(x1, x2, e1, e2, Wp, P);
    reduce_bias<<<1024, 256, 0, stream>>>(P, bp, hbuf, stats);

    // ---- batchnorm + relu + l2norm ----
    bn_stats<<<256, 256, 0, stream>>>(hbuf, stats);
    bn_norm_l2<<<4096, 256, 0, stream>>>(hbuf, stats, gamma, beta);

    // ---- similarity GEMMs ----
    gemm_sim<<<dim3(40, 8), 256, 0, stream>>>(hbuf, Kp, Ke);

    // ---- sparse K structure (build_csr zeroes degcnt) ----
    build_csr<<<8, 256, 0, stream>>>(src1, dst1, src2, dst2,
                                     off1, lst1, off2, lst2,
                                     rep1g, rep2g, coff1, clst1, coff2, clst2,
                                     degcnt);
    pairdeg<<<dim3(144, 8), 256, 0, stream>>>(src1, dst1, src2, dst2,
                                              rep1g, rep2g, coff1, clst1, coff2, clst2,
                                              Ke, degcnt);
    deg_fin<<<128, 256, 0, stream>>>(degcnt, Kp, deg, kdiag);

    // ---- GNN layers (fused gather+MLP) + sinkhorns ----
    layer_k<1><<<dim3(64, 8), 256, 0, stream>>>(off1, lst1, off2, lst2, dst1, dst2,
                                                Ke, kdiag, kdiag, deg, W0, b0, S0, c0, xA, vbuf);
    sinkhorn_k<64, 512, false><<<8, 512, 0, stream>>>(vbuf, xA, nullptr, nullptr, nullptr);

    layer_k<17><<<dim3(64, 8), 256, 0, stream>>>(off1, lst1, off2, lst2, dst1, dst2,
                                                 Ke, xA, kdiag, deg, W1, b1, S1, c1, xB, vbuf);
    sinkhorn_k<64, 512, false><<<8, 512, 0, stream>>>(vbuf, xB, nullptr, nullptr, nullptr);

    layer_k<17><<<dim3(64, 8), 256, 0, stream>>>(off1, lst1, off2, lst2, dst1, dst2,
                                                 Ke, xB, kdiag, deg, W2, b2, S2, c2, xA, vbuf);
    sinkhorn_k<64, 512, false><<<8, 512, 0, stream>>>(vbuf, xA, nullptr, nullptr, nullptr);

    // ---- final: fused projection + bin-augmented sinkhorn + normalize ----
    sinkhorn_k<65, 576, true><<<8, 576, 0, stream>>>(xA, out, binv, Wc, bc);
    norm_out<<<1, 1024, 0, stream>>>(out);
}